// Round 6
// baseline (673.982 us; speedup 1.0000x reference)
//
#include <hip/hip_runtime.h>

#define N_NODES   100000
#define N_EDGES   800000
#define N_ETYPES  5
#define IN_DIM    23
#define FPAD      24                    // feat dims padded to 24 (48 B bf16 rows)
#define HID_DIM   128
#define OUT_DIM   64
#define NUM_GRAPHS 64
#define NBKT      391                   // ceil(100000/256) dst buckets of 256 nodes
#define PBLK      125                   // partition blocks per etype
#define CHUNK     6400                  // edges per partition block (125*6400 = 800000)
#define PN        (N_ETYPES*NBKT*PBLK)  // 244,375 histogram entries
#define SCAN_NBLK ((PN + 1023) / 1024)  // 239
#define TOT_EDGES (N_ETYPES*N_EDGES)    // 4,000,000
#define BKT_CAP   3072                  // max edges per (etype,bucket); mean 2048, sigma 45

// NOTE (measured r3): bulk LDS float atomics ~3.5 cyc/lane on gfx950 — push-aggregation
// via ds_atomic is 30x slower than pull-gather. All aggregation is atomic-free pull.
// NOTE (measured r4/r5): L3 row-gather needs occupancy: 391 blk -> 16.6% occ, 1.45 TB/s;
// 1564 blk -> 65% occ, 3.42 TB/s. This round: 3128 blk -> target full 32 waves/CU.

__device__ __forceinline__ unsigned short f2bf(float x) {
    unsigned u = __float_as_uint(x);
    unsigned r = (u + 0x7FFFu + ((u >> 16) & 1u)) >> 16;   // RNE
    return (unsigned short)r;
}
__device__ __forceinline__ float bf2f(unsigned short h) {
    return __uint_as_float(((unsigned)h) << 16);
}

typedef __attribute__((ext_vector_type(8))) short bf16x8;
typedef __attribute__((ext_vector_type(4))) float f32x4;

// ---------------- feat -> bf16 table, padded to 24 dims ----------------
__global__ __launch_bounds__(256) void cvt_feat_k(const float* __restrict__ feat,
                                                  unsigned short* __restrict__ fb24) {
    int i = blockIdx.x * 256 + threadIdx.x;
    if (i < N_NODES * FPAD) {
        int n = i / FPAD, d = i - n * FPAD;
        fb24[i] = (d < IN_DIM) ? f2bf(feat[n * IN_DIM + d]) : (unsigned short)0;
    }
}

// ---------------- partition pass 1: per-block bucket histogram ----------------
__global__ __launch_bounds__(256) void part1_k(const int* __restrict__ dst,
                                               int* __restrict__ hp) {
    __shared__ int hist[NBKT];
    int e = blockIdx.y, blk = blockIdx.x, t = threadIdx.x;
    for (int b = t; b < NBKT; b += 256) hist[b] = 0;
    __syncthreads();
    const int* dp = dst + e * N_EDGES + blk * CHUNK;
    for (int k = t; k < CHUNK; k += 256) atomicAdd(&hist[dp[k] >> 8], 1);
    __syncthreads();
    for (int b = t; b < NBKT; b += 256) hp[(e * NBKT + b) * PBLK + blk] = hist[b];
}

// ---------------- exclusive scan over 244,375 ----------------
__global__ __launch_bounds__(256) void scan1_k(const int* __restrict__ in,
                                               int* __restrict__ out,
                                               int* __restrict__ bsum) {
    __shared__ int ls[256];
    int t = threadIdx.x;
    int base = blockIdx.x * 1024 + t * 4;
    int v[4]; int s = 0;
    for (int j = 0; j < 4; j++) { int i = base + j; v[j] = (i < PN) ? in[i] : 0; s += v[j]; }
    ls[t] = s; __syncthreads();
    for (int o = 1; o < 256; o <<= 1) {
        int x = (t >= o) ? ls[t - o] : 0;
        __syncthreads();
        ls[t] += x;
        __syncthreads();
    }
    int run = (t > 0) ? ls[t - 1] : 0;
    if (t == 255) bsum[blockIdx.x] = ls[255];
    for (int j = 0; j < 4; j++) { int i = base + j; if (i < PN) out[i] = run; run += v[j]; }
}

__global__ __launch_bounds__(256) void scan2_k(int* __restrict__ bsum) {
    __shared__ int ls[256];
    int t = threadIdx.x;
    int v = (t < SCAN_NBLK) ? bsum[t] : 0;
    ls[t] = v; __syncthreads();
    for (int o = 1; o < 256; o <<= 1) {
        int x = (t >= o) ? ls[t - o] : 0;
        __syncthreads();
        ls[t] += x;
        __syncthreads();
    }
    if (t < SCAN_NBLK) bsum[t] = (t > 0) ? ls[t - 1] : 0;
}

__global__ __launch_bounds__(256) void scan3_k(int* __restrict__ off,
                                               const int* __restrict__ bsum) {
    int i = blockIdx.x * 256 + threadIdx.x;
    if (i < PN) off[i] += bsum[i >> 10];
}

// ---------------- partition pass 2: blocked contiguous scatter ----------------
__global__ __launch_bounds__(256) void part2_k(const int* __restrict__ src,
                                               const int* __restrict__ dst,
                                               const int* __restrict__ off,
                                               unsigned* __restrict__ ep) {
    __shared__ int cur[NBKT];
    int e = blockIdx.y, blk = blockIdx.x, t = threadIdx.x;
    for (int b = t; b < NBKT; b += 256) cur[b] = off[(e * NBKT + b) * PBLK + blk];
    __syncthreads();
    const int* dp = dst + e * N_EDGES + blk * CHUNK;
    const int* sp = src + e * N_EDGES + blk * CHUNK;
    for (int k = t; k < CHUNK; k += 256) {
        int d = dp[k], s = sp[k];
        int b = d >> 8;
        int pos = atomicAdd(&cur[b], 1);
        ep[pos] = (unsigned)s | ((unsigned)(d & 255) << 24);
    }
}

// ---------------- per-bucket counting sort -> node-sorted CSR + NOFF/DEG/INV ---
__global__ __launch_bounds__(256) void sort_k(const int* __restrict__ off,
                                              const unsigned* __restrict__ ep,
                                              unsigned* __restrict__ csr,
                                              int* __restrict__ noff,
                                              int* __restrict__ degn,
                                              float* __restrict__ inv) {
    __shared__ unsigned recs[BKT_CAP];
    __shared__ int hist[256];
    __shared__ int scn[256];
    __shared__ int curp[256];
    int b = blockIdx.x, e = blockIdx.y, t = threadIdx.x;
    int lin = (e * NBKT + b) * PBLK;
    int S = off[lin];
    int E = (lin == PN - PBLK) ? TOT_EDGES : off[lin + PBLK];
    int cnt = E - S;
    hist[t] = 0;
    __syncthreads();
    for (int i = t; i < cnt; i += 256) {
        unsigned r = ep[S + i];
        recs[i] = r;
        atomicAdd(&hist[r >> 24], 1);
    }
    __syncthreads();
    scn[t] = hist[t];
    __syncthreads();
    for (int o = 1; o < 256; o <<= 1) {
        int x = (t >= o) ? scn[t - o] : 0;
        __syncthreads();
        scn[t] += x;
        __syncthreads();
    }
    int excl = scn[t] - hist[t];
    curp[t] = excl;
    int n = b * 256 + t;
    if (n < N_NODES) {
        noff[e * N_NODES + n] = S + excl;
        degn[e * N_NODES + n] = hist[t];
        inv[e * N_NODES + n]  = 1.f / (float)(hist[t] + 1);
    }
    __syncthreads();
    for (int i = t; i < cnt; i += 256) {
        unsigned r = recs[i];
        int pos = atomicAdd(&curp[r >> 24], 1);
        csr[S + pos] = r & 0xFFFFFFu;
    }
}

// ---------------- layer1 pull-aggregate: AGG1[e,n,0:24] = inv * sum fb24[src] ----
__global__ __launch_bounds__(256) void agg1_k(const int* __restrict__ noff,
                                              const int* __restrict__ degn,
                                              const unsigned* __restrict__ csr,
                                              const unsigned short* __restrict__ fb24,
                                              const float* __restrict__ inv,
                                              float* __restrict__ agg1) {
    int e = blockIdx.y;
    int t = threadIdx.x;
    int lane = t & 15;
    int n = blockIdx.x * 16 + (t >> 4);
    int idx = e * N_NODES + n;
    if (lane >= 12) return;
    int st = noff[idx];
    int cnt = degn[idx];
    float a0 = 0.f, a1 = 0.f;
    int k = 0;
    for (; k + 1 < cnt; k += 2) {
        int s0 = csr[st + k];
        int s1 = csr[st + k + 1];
        ushort2 v0 = *(const ushort2*)&fb24[s0 * FPAD + lane * 2];
        ushort2 v1 = *(const ushort2*)&fb24[s1 * FPAD + lane * 2];
        a0 += bf2f(v0.x) + bf2f(v1.x);
        a1 += bf2f(v0.y) + bf2f(v1.y);
    }
    if (k < cnt) {
        int s0 = csr[st + k];
        ushort2 v0 = *(const ushort2*)&fb24[s0 * FPAD + lane * 2];
        a0 += bf2f(v0.x);
        a1 += bf2f(v0.y);
    }
    float iv = inv[idx];
    float2 o; o.x = a0 * iv; o.y = a1 * iv;
    *(float2*)&agg1[(size_t)idx * FPAD + lane * 2] = o;
}

// ---------------- layer1 GEMM -> H1 (bf16 out); AGG1 has stride 24 ----------------
__global__ __launch_bounds__(256) void gemm1_k(const float* __restrict__ feat,
                                               const float* __restrict__ agg1,
                                               const float* __restrict__ inv,
                                               const float* __restrict__ W1,
                                               const float* __restrict__ b1,
                                               unsigned short* __restrict__ h1b) {
    __shared__ float xs[128 * 25];
    __shared__ float wl[IN_DIM * HID_DIM];
    int t = threadIdx.x;
    int node0 = blockIdx.x * 128;
    int ng = t >> 3;
    int o  = t & 7;
    float acc[4][16];
    for (int i = 0; i < 4; i++)
        for (int j = 0; j < 16; j++) acc[i][j] = 0.f;

    for (int e = 0; e < N_ETYPES; e++) {
        __syncthreads();
        for (int j = t; j < IN_DIM * HID_DIM; j += 256)
            wl[j] = W1[e * IN_DIM * HID_DIM + j];
        for (int j = t; j < 128 * IN_DIM; j += 256) {
            int nl = j / IN_DIM;
            int k  = j - nl * IN_DIM;
            int gn = node0 + nl;
            int cn = gn < N_NODES ? gn : N_NODES - 1;
            xs[nl * 25 + k] = agg1[(size_t)(e * N_NODES + cn) * FPAD + k]
                            + feat[cn * IN_DIM + k] * inv[e * N_NODES + cn];
        }
        __syncthreads();
        for (int j = 0; j < 16; j++) {
            float bb = b1[e * HID_DIM + o * 16 + j];
            for (int i = 0; i < 4; i++) acc[i][j] += bb;
        }
        for (int k = 0; k < IN_DIM; k++) {
            float xv[4];
            for (int i = 0; i < 4; i++) xv[i] = xs[(ng * 4 + i) * 25 + k];
            for (int j4 = 0; j4 < 4; j4++) {
                float4 w = *(const float4*)&wl[k * HID_DIM + o * 16 + j4 * 4];
                for (int i = 0; i < 4; i++) {
                    acc[i][j4 * 4 + 0] += xv[i] * w.x;
                    acc[i][j4 * 4 + 1] += xv[i] * w.y;
                    acc[i][j4 * 4 + 2] += xv[i] * w.z;
                    acc[i][j4 * 4 + 3] += xv[i] * w.w;
                }
            }
        }
    }
    for (int i = 0; i < 4; i++) {
        int gn = node0 + ng * 4 + i;
        if (gn < N_NODES) {
            for (int j4 = 0; j4 < 4; j4++) {
                ushort4 v;
                v.x = f2bf(fmaxf(acc[i][j4 * 4 + 0], 0.f));
                v.y = f2bf(fmaxf(acc[i][j4 * 4 + 1], 0.f));
                v.z = f2bf(fmaxf(acc[i][j4 * 4 + 2], 0.f));
                v.w = f2bf(fmaxf(acc[i][j4 * 4 + 3], 0.f));
                *(ushort4*)&h1b[gn * HID_DIM + o * 16 + j4 * 4] = v;
            }
        }
    }
}

// ---------------- layer2 transform GEMM (MFMA bf16, all etypes fused) ----------
// Block = 64 nodes, 4 waves; wave w owns rows w*16..w*16+15. A staged once
// (16 KB), W2^T staged per etype (16 KB). mfma_f32_16x16x32_bf16:
//   A[m=lane&15][k=quad*8+j], B[n=lane&15][k=quad*8+j], D col=lane&15 row=quad*4+reg.
__global__ __launch_bounds__(256) void gemm2_k(const unsigned short* __restrict__ h1b,
                                               const float* __restrict__ W2,
                                               unsigned short* __restrict__ t2b) {
    __shared__ unsigned short As[64 * 128];   // 16 KB [node][k]
    __shared__ unsigned short Wt[64 * 128];   // 16 KB [n][k]  (= W2[e]^T, bf16)
    int t = threadIdx.x;
    int node0 = blockIdx.x * 64;
    int w = t >> 6, lane = t & 63;
    int m = lane & 15, quad = lane >> 4;

    for (int j = t; j < 64 * 32; j += 256) {          // 2048 ushort4 chunks
        int n = j >> 5, c4 = (j & 31) * 4;
        int gn = node0 + n;
        int cn = gn < N_NODES ? gn : N_NODES - 1;
        *(ushort4*)&As[n * 128 + c4] = *(const ushort4*)&h1b[cn * HID_DIM + c4];
    }
    __syncthreads();
    bf16x8 a[4];
    for (int ks = 0; ks < 4; ks++)
        a[ks] = *(const bf16x8*)&As[(w * 16 + m) * 128 + ks * 32 + quad * 8];

    for (int e = 0; e < N_ETYPES; e++) {
        __syncthreads();                               // protect Wt from prev readers
        for (int j = t; j < 64 * 128; j += 256) {
            int n = j >> 7, k = j & 127;
            Wt[n * 128 + k] = f2bf(W2[(e * HID_DIM + k) * OUT_DIM + n]);
        }
        __syncthreads();
        unsigned short* out = t2b + (size_t)e * N_NODES * OUT_DIM;
        for (int nt = 0; nt < 4; nt++) {
            f32x4 c = {0.f, 0.f, 0.f, 0.f};
            for (int ks = 0; ks < 4; ks++) {
                bf16x8 b = *(const bf16x8*)&Wt[(nt * 16 + m) * 128 + ks * 32 + quad * 8];
                c = __builtin_amdgcn_mfma_f32_16x16x32_bf16(a[ks], b, c, 0, 0, 0);
            }
            for (int r = 0; r < 4; r++) {
                int gn = node0 + w * 16 + quad * 4 + r;
                if (gn < N_NODES) out[gn * OUT_DIM + nt * 16 + m] = f2bf(c[r]);
            }
        }
    }
}

// ---------------- layer2 pull + per-graph pool, eighth-bucket blocks ----------
// grid (NBKT, 8): block = 32 nodes x all 5 etypes. 16 groups x 16 lanes x ushort4;
// per-graph partials in 4 register slots (gid sorted), LDS tree-reduce, 256 atomics/blk.
__global__ __launch_bounds__(256) void gather2_k(const int* __restrict__ noff,
                                                 const int* __restrict__ degn,
                                                 const float* __restrict__ inv,
                                                 const unsigned* __restrict__ csr,
                                                 const unsigned short* __restrict__ t2b,
                                                 const int* __restrict__ gid,
                                                 float* __restrict__ gsum) {
    __shared__ float4 red4[16 * 4 * 16];    // 16 KB: [ng][slot][lane]
    int b = blockIdx.x, qb = blockIdx.y, t = threadIdx.x;
    int lane = t & 15, ng = t >> 4;
    int nbase = b * 256 + qb * 32;
    int gbase = nbase < N_NODES ? nbase : N_NODES - 1;
    int g0 = gid[gbase];
    float4 sa0 = {0,0,0,0}, sa1 = {0,0,0,0}, sa2 = {0,0,0,0}, sa3 = {0,0,0,0};

    for (int pass = 0; pass < 2; pass++) {
        int n = nbase + pass * 16 + ng;
        if (n >= N_NODES) break;
        float4 f = {0,0,0,0};
        for (int e = 0; e < N_ETYPES; e++) {
            int idx = e * N_NODES + n;
            int st = noff[idx];
            int cnt = degn[idx];
            float iv = inv[idx];
            const unsigned short* base = t2b + (size_t)e * N_NODES * OUT_DIM;
            ushort4 sv = *(const ushort4*)&base[n * OUT_DIM + lane * 4];
            float ax = bf2f(sv.x), ay = bf2f(sv.y), az = bf2f(sv.z), aw = bf2f(sv.w);
            int k = 0;
            for (; k + 1 < cnt; k += 2) {
                int sA = csr[st + k];
                int sB = csr[st + k + 1];
                ushort4 vA = *(const ushort4*)&base[sA * OUT_DIM + lane * 4];
                ushort4 vB = *(const ushort4*)&base[sB * OUT_DIM + lane * 4];
                ax += bf2f(vA.x) + bf2f(vB.x);
                ay += bf2f(vA.y) + bf2f(vB.y);
                az += bf2f(vA.z) + bf2f(vB.z);
                aw += bf2f(vA.w) + bf2f(vB.w);
            }
            if (k < cnt) {
                int sA = csr[st + k];
                ushort4 vA = *(const ushort4*)&base[sA * OUT_DIM + lane * 4];
                ax += bf2f(vA.x); ay += bf2f(vA.y); az += bf2f(vA.z); aw += bf2f(vA.w);
            }
            f.x += iv * ax; f.y += iv * ay; f.z += iv * az; f.w += iv * aw;
        }
        int slot = gid[n] - g0;
        float m0 = (slot == 0) ? 1.f : 0.f;
        float m1 = (slot == 1) ? 1.f : 0.f;
        float m2 = (slot == 2) ? 1.f : 0.f;
        float m3 = (slot == 3) ? 1.f : 0.f;
        sa0.x += m0 * f.x; sa0.y += m0 * f.y; sa0.z += m0 * f.z; sa0.w += m0 * f.w;
        sa1.x += m1 * f.x; sa1.y += m1 * f.y; sa1.z += m1 * f.z; sa1.w += m1 * f.w;
        sa2.x += m2 * f.x; sa2.y += m2 * f.y; sa2.z += m2 * f.z; sa2.w += m2 * f.w;
        sa3.x += m3 * f.x; sa3.y += m3 * f.y; sa3.z += m3 * f.z; sa3.w += m3 * f.w;
        if (slot > 3) {                      // statistically never
            atomicAdd(&gsum[(g0 + slot) * 64 + lane * 4 + 0], f.x);
            atomicAdd(&gsum[(g0 + slot) * 64 + lane * 4 + 1], f.y);
            atomicAdd(&gsum[(g0 + slot) * 64 + lane * 4 + 2], f.z);
            atomicAdd(&gsum[(g0 + slot) * 64 + lane * 4 + 3], f.w);
        }
    }
    red4[(ng * 4 + 0) * 16 + lane] = sa0;
    red4[(ng * 4 + 1) * 16 + lane] = sa1;
    red4[(ng * 4 + 2) * 16 + lane] = sa2;
    red4[(ng * 4 + 3) * 16 + lane] = sa3;
    __syncthreads();
    const float* red = (const float*)red4;
    int slot = t >> 6, d = t & 63;
    float s = 0.f;
    for (int j = 0; j < 16; j++) s += red[(j * 4 + slot) * 64 + d];
    int g = g0 + slot;
    if (g < NUM_GRAPHS) atomicAdd(&gsum[g * 64 + d], s);
}

// ---------------- per-graph node counts ----------------
__global__ __launch_bounds__(256) void gcnt_k(const int* __restrict__ gid,
                                              float* __restrict__ gcnt) {
    __shared__ int h[NUM_GRAPHS];
    int b = blockIdx.x, t = threadIdx.x;
    if (t < NUM_GRAPHS) h[t] = 0;
    __syncthreads();
    int n = b * 256 + t;
    if (n < N_NODES) atomicAdd(&h[gid[n]], 1);
    __syncthreads();
    if (t < NUM_GRAPHS && h[t] > 0) atomicAdd(&gcnt[t], (float)h[t]);
}

__global__ __launch_bounds__(256) void final_k(const float* __restrict__ gsum,
                                               const float* __restrict__ gcnt,
                                               const float* __restrict__ b2,
                                               float* __restrict__ out) {
    int idx = blockIdx.x * 256 + threadIdx.x;
    if (idx >= NUM_GRAPHS * OUT_DIM) return;
    int d = idx & 63;
    float B2 = 0.f;
    for (int e = 0; e < N_ETYPES; e++) B2 += b2[e * OUT_DIM + d];
    float c = gcnt[idx >> 6];
    out[idx] = (gsum[idx] + c * B2) / fmaxf(c, 1.0f);
}

extern "C" void kernel_launch(void* const* d_in, const int* in_sizes, int n_in,
                              void* d_out, int out_size, void* d_ws, size_t ws_size,
                              hipStream_t stream) {
    const float* feat = (const float*)d_in[0];
    const int*   src  = (const int*)d_in[1];
    const int*   dst  = (const int*)d_in[2];
    const int*   gid  = (const int*)d_in[3];
    const float* W1   = (const float*)d_in[4];
    const float* b1   = (const float*)d_in[5];
    const float* W2   = (const float*)d_in[6];
    const float* b2   = (const float*)d_in[7];

    float* ws = (float*)d_ws;
    int*            HP   = (int*)ws;                         //   244,375 (pad 245,000)
    int*            OFFP = (int*)ws + 245000;                //   244,375 (pad 245,000)
    int*            BSUM = (int*)ws + 490000;                //   512
    float*          INV  = ws + 490512;                      //   500,000
    int*            NOFF = (int*)ws + 990512;                //   500,000
    int*            DEGN = (int*)ws + 1490512;               //   500,000
    unsigned short* FB24 = (unsigned short*)(ws + 1990512);  //   2.4M bf16 = 1,200,000 f
    float*          GSUM = ws + 3190512;                     //   4,096
    float*          GCNT = ws + 3194608;                     //   64
    unsigned*       EP   = (unsigned*)(ws + 3195000);        //   4,000,000
    float*          AGG1 = ws + 7195000;                     //  12,000,000 (ends 19,195,000)
    unsigned short* T2B  = (unsigned short*)(ws + 3195000);  //  32M bf16 = 16,000,000 f
                    // T2B aliases EP (dead after sort_k) + AGG1 (dead after gemm1_k)
    unsigned short* H1B  = (unsigned short*)(ws + 19195000); //  12.8M bf16 = 6,400,000 f
    unsigned*       CSR  = (unsigned*)(ws + 25595000);       //   4,000,000
    // total 29,595,000 floats = 118.4 MB

    hipMemsetAsync(GSUM, 0, (size_t)(4096 + 64) * sizeof(float), stream);

    cvt_feat_k<<<(N_NODES * FPAD + 255) / 256, 256, 0, stream>>>(feat, FB24);
    part1_k<<<dim3(PBLK, N_ETYPES), 256, 0, stream>>>(dst, HP);
    scan1_k<<<SCAN_NBLK, 256, 0, stream>>>(HP, OFFP, BSUM);
    scan2_k<<<1, 256, 0, stream>>>(BSUM);
    scan3_k<<<(PN + 255) / 256, 256, 0, stream>>>(OFFP, BSUM);
    part2_k<<<dim3(PBLK, N_ETYPES), 256, 0, stream>>>(src, dst, OFFP, EP);
    sort_k<<<dim3(NBKT, N_ETYPES), 256, 0, stream>>>(OFFP, EP, CSR, NOFF, DEGN, INV);

    agg1_k<<<dim3(6250, N_ETYPES), 256, 0, stream>>>(NOFF, DEGN, CSR, FB24, INV, AGG1);
    gemm1_k<<<782, 256, 0, stream>>>(feat, AGG1, INV, W1, b1, H1B);
    gemm2_k<<<(N_NODES + 63) / 64, 256, 0, stream>>>(H1B, W2, T2B);
    gather2_k<<<dim3(NBKT, 8), 256, 0, stream>>>(NOFF, DEGN, INV, CSR, T2B, gid, GSUM);

    gcnt_k<<<391, 256, 0, stream>>>(gid, GCNT);
    final_k<<<16, 256, 0, stream>>>(GSUM, GCNT, b2, (float*)d_out);
}

// Round 7
// 574.163 us; speedup vs baseline: 1.1739x; 1.1739x over previous
//
#include <hip/hip_runtime.h>

#define N_NODES   100000
#define N_EDGES   800000
#define N_ETYPES  5
#define IN_DIM    23
#define FPAD      24                    // feat dims padded to 24 (48 B bf16 rows)
#define HID_DIM   128
#define OUT_DIM   64
#define NUM_GRAPHS 64
#define NBKT      391                   // ceil(100000/256) dst buckets of 256 nodes
#define PBLK      125                   // partition blocks per etype
#define CHUNK     6400                  // edges per partition block (125*6400 = 800000)
#define PN        (N_ETYPES*NBKT*PBLK)  // 244,375 histogram entries
#define SCAN_NBLK ((PN + 1023) / 1024)  // 239
#define TOT_EDGES (N_ETYPES*N_EDGES)    // 4,000,000
#define BKT_CAP   3072                  // max edges per (etype,bucket); mean 2048, sigma 45
#define ASTR      136                   // LDS tile stride: 128+8 ushorts = 272 B -> conflict-free

// NOTE (measured r3): bulk LDS float atomics ~3.5 cyc/lane on gfx950 — push-aggregation
// via ds_atomic is 30x slower than pull-gather. All aggregation is atomic-free pull.
// NOTE (measured r4/r5): L3 row-gather needs occupancy: 391 blk -> 16.6% occ, 1.45 TB/s;
// 1564 blk -> 65% occ, 3.42 TB/s.
// NOTE (measured r6): unpadded [node][128] bf16 LDS tiles give 16-way bank conflicts on
// MFMA fragment ds_read_b128 (1.47e7 SQ_LDS_BANK_CONFLICT, MfmaUtil 2.2%). Stride 136
// (272 B rows, bank step 4) makes the (m,quad) lane map exactly uniform over 32 banks.

__device__ __forceinline__ unsigned short f2bf(float x) {
    unsigned u = __float_as_uint(x);
    unsigned r = (u + 0x7FFFu + ((u >> 16) & 1u)) >> 16;   // RNE
    return (unsigned short)r;
}
__device__ __forceinline__ float bf2f(unsigned short h) {
    return __uint_as_float(((unsigned)h) << 16);
}

typedef __attribute__((ext_vector_type(8))) short bf16x8;
typedef __attribute__((ext_vector_type(4))) float f32x4;

// ---------------- feat -> bf16 table, padded to 24 dims ----------------
__global__ __launch_bounds__(256) void cvt_feat_k(const float* __restrict__ feat,
                                                  unsigned short* __restrict__ fb24) {
    int i = blockIdx.x * 256 + threadIdx.x;
    if (i < N_NODES * FPAD) {
        int n = i / FPAD, d = i - n * FPAD;
        fb24[i] = (d < IN_DIM) ? f2bf(feat[n * IN_DIM + d]) : (unsigned short)0;
    }
}

// ---------------- W2 -> bf16 transposed table: w2tb[e][n][k] ----------------
__global__ __launch_bounds__(256) void cvt_w2t_k(const float* __restrict__ W2,
                                                 unsigned short* __restrict__ w2tb) {
    int i = blockIdx.x * 256 + threadIdx.x;
    if (i < N_ETYPES * OUT_DIM * HID_DIM) {
        int e = i / (OUT_DIM * HID_DIM);
        int r = i - e * (OUT_DIM * HID_DIM);
        int n = r >> 7, k = r & 127;
        w2tb[i] = f2bf(W2[(e * HID_DIM + k) * OUT_DIM + n]);
    }
}

// ---------------- partition pass 1: per-block bucket histogram ----------------
__global__ __launch_bounds__(256) void part1_k(const int* __restrict__ dst,
                                               int* __restrict__ hp) {
    __shared__ int hist[NBKT];
    int e = blockIdx.y, blk = blockIdx.x, t = threadIdx.x;
    for (int b = t; b < NBKT; b += 256) hist[b] = 0;
    __syncthreads();
    const int* dp = dst + e * N_EDGES + blk * CHUNK;
    for (int k = t; k < CHUNK; k += 256) atomicAdd(&hist[dp[k] >> 8], 1);
    __syncthreads();
    for (int b = t; b < NBKT; b += 256) hp[(e * NBKT + b) * PBLK + blk] = hist[b];
}

// ---------------- exclusive scan over 244,375 ----------------
__global__ __launch_bounds__(256) void scan1_k(const int* __restrict__ in,
                                               int* __restrict__ out,
                                               int* __restrict__ bsum) {
    __shared__ int ls[256];
    int t = threadIdx.x;
    int base = blockIdx.x * 1024 + t * 4;
    int v[4]; int s = 0;
    for (int j = 0; j < 4; j++) { int i = base + j; v[j] = (i < PN) ? in[i] : 0; s += v[j]; }
    ls[t] = s; __syncthreads();
    for (int o = 1; o < 256; o <<= 1) {
        int x = (t >= o) ? ls[t - o] : 0;
        __syncthreads();
        ls[t] += x;
        __syncthreads();
    }
    int run = (t > 0) ? ls[t - 1] : 0;
    if (t == 255) bsum[blockIdx.x] = ls[255];
    for (int j = 0; j < 4; j++) { int i = base + j; if (i < PN) out[i] = run; run += v[j]; }
}

__global__ __launch_bounds__(256) void scan2_k(int* __restrict__ bsum) {
    __shared__ int ls[256];
    int t = threadIdx.x;
    int v = (t < SCAN_NBLK) ? bsum[t] : 0;
    ls[t] = v; __syncthreads();
    for (int o = 1; o < 256; o <<= 1) {
        int x = (t >= o) ? ls[t - o] : 0;
        __syncthreads();
        ls[t] += x;
        __syncthreads();
    }
    if (t < SCAN_NBLK) bsum[t] = (t > 0) ? ls[t - 1] : 0;
}

__global__ __launch_bounds__(256) void scan3_k(int* __restrict__ off,
                                               const int* __restrict__ bsum) {
    int i = blockIdx.x * 256 + threadIdx.x;
    if (i < PN) off[i] += bsum[i >> 10];
}

// ---------------- partition pass 2: blocked contiguous scatter ----------------
__global__ __launch_bounds__(256) void part2_k(const int* __restrict__ src,
                                               const int* __restrict__ dst,
                                               const int* __restrict__ off,
                                               unsigned* __restrict__ ep) {
    __shared__ int cur[NBKT];
    int e = blockIdx.y, blk = blockIdx.x, t = threadIdx.x;
    for (int b = t; b < NBKT; b += 256) cur[b] = off[(e * NBKT + b) * PBLK + blk];
    __syncthreads();
    const int* dp = dst + e * N_EDGES + blk * CHUNK;
    const int* sp = src + e * N_EDGES + blk * CHUNK;
    for (int k = t; k < CHUNK; k += 256) {
        int d = dp[k], s = sp[k];
        int b = d >> 8;
        int pos = atomicAdd(&cur[b], 1);
        ep[pos] = (unsigned)s | ((unsigned)(d & 255) << 24);
    }
}

// ---------------- per-bucket counting sort -> node-sorted CSR + NOFF/DEG/INV ---
__global__ __launch_bounds__(256) void sort_k(const int* __restrict__ off,
                                              const unsigned* __restrict__ ep,
                                              unsigned* __restrict__ csr,
                                              int* __restrict__ noff,
                                              int* __restrict__ degn,
                                              float* __restrict__ inv) {
    __shared__ unsigned recs[BKT_CAP];
    __shared__ int hist[256];
    __shared__ int scn[256];
    __shared__ int curp[256];
    int b = blockIdx.x, e = blockIdx.y, t = threadIdx.x;
    int lin = (e * NBKT + b) * PBLK;
    int S = off[lin];
    int E = (lin == PN - PBLK) ? TOT_EDGES : off[lin + PBLK];
    int cnt = E - S;
    hist[t] = 0;
    __syncthreads();
    for (int i = t; i < cnt; i += 256) {
        unsigned r = ep[S + i];
        recs[i] = r;
        atomicAdd(&hist[r >> 24], 1);
    }
    __syncthreads();
    scn[t] = hist[t];
    __syncthreads();
    for (int o = 1; o < 256; o <<= 1) {
        int x = (t >= o) ? scn[t - o] : 0;
        __syncthreads();
        scn[t] += x;
        __syncthreads();
    }
    int excl = scn[t] - hist[t];
    curp[t] = excl;
    int n = b * 256 + t;
    if (n < N_NODES) {
        noff[e * N_NODES + n] = S + excl;
        degn[e * N_NODES + n] = hist[t];
        inv[e * N_NODES + n]  = 1.f / (float)(hist[t] + 1);
    }
    __syncthreads();
    for (int i = t; i < cnt; i += 256) {
        unsigned r = recs[i];
        int pos = atomicAdd(&curp[r >> 24], 1);
        csr[S + pos] = r & 0xFFFFFFu;
    }
}

// ---------------- layer1 pull-aggregate: AGG1[e,n,0:24] = inv * sum fb24[src] ----
__global__ __launch_bounds__(256) void agg1_k(const int* __restrict__ noff,
                                              const int* __restrict__ degn,
                                              const unsigned* __restrict__ csr,
                                              const unsigned short* __restrict__ fb24,
                                              const float* __restrict__ inv,
                                              float* __restrict__ agg1) {
    int e = blockIdx.y;
    int t = threadIdx.x;
    int lane = t & 15;
    int n = blockIdx.x * 16 + (t >> 4);
    int idx = e * N_NODES + n;
    if (lane >= 12) return;
    int st = noff[idx];
    int cnt = degn[idx];
    float a0 = 0.f, a1 = 0.f;
    int k = 0;
    for (; k + 1 < cnt; k += 2) {
        int s0 = csr[st + k];
        int s1 = csr[st + k + 1];
        ushort2 v0 = *(const ushort2*)&fb24[s0 * FPAD + lane * 2];
        ushort2 v1 = *(const ushort2*)&fb24[s1 * FPAD + lane * 2];
        a0 += bf2f(v0.x) + bf2f(v1.x);
        a1 += bf2f(v0.y) + bf2f(v1.y);
    }
    if (k < cnt) {
        int s0 = csr[st + k];
        ushort2 v0 = *(const ushort2*)&fb24[s0 * FPAD + lane * 2];
        a0 += bf2f(v0.x);
        a1 += bf2f(v0.y);
    }
    float iv = inv[idx];
    float2 o; o.x = a0 * iv; o.y = a1 * iv;
    *(float2*)&agg1[(size_t)idx * FPAD + lane * 2] = o;
}

// ---------------- layer1 GEMM -> H1 (bf16 out); AGG1 has stride 24 ----------------
__global__ __launch_bounds__(256) void gemm1_k(const float* __restrict__ feat,
                                               const float* __restrict__ agg1,
                                               const float* __restrict__ inv,
                                               const float* __restrict__ W1,
                                               const float* __restrict__ b1,
                                               unsigned short* __restrict__ h1b) {
    __shared__ float xs[128 * 25];
    __shared__ float wl[IN_DIM * HID_DIM];
    int t = threadIdx.x;
    int node0 = blockIdx.x * 128;
    int ng = t >> 3;
    int o  = t & 7;
    float acc[4][16];
    for (int i = 0; i < 4; i++)
        for (int j = 0; j < 16; j++) acc[i][j] = 0.f;

    for (int e = 0; e < N_ETYPES; e++) {
        __syncthreads();
        for (int j = t; j < IN_DIM * HID_DIM; j += 256)
            wl[j] = W1[e * IN_DIM * HID_DIM + j];
        for (int j = t; j < 128 * IN_DIM; j += 256) {
            int nl = j / IN_DIM;
            int k  = j - nl * IN_DIM;
            int gn = node0 + nl;
            int cn = gn < N_NODES ? gn : N_NODES - 1;
            xs[nl * 25 + k] = agg1[(size_t)(e * N_NODES + cn) * FPAD + k]
                            + feat[cn * IN_DIM + k] * inv[e * N_NODES + cn];
        }
        __syncthreads();
        for (int j = 0; j < 16; j++) {
            float bb = b1[e * HID_DIM + o * 16 + j];
            for (int i = 0; i < 4; i++) acc[i][j] += bb;
        }
        for (int k = 0; k < IN_DIM; k++) {
            float xv[4];
            for (int i = 0; i < 4; i++) xv[i] = xs[(ng * 4 + i) * 25 + k];
            for (int j4 = 0; j4 < 4; j4++) {
                float4 w = *(const float4*)&wl[k * HID_DIM + o * 16 + j4 * 4];
                for (int i = 0; i < 4; i++) {
                    acc[i][j4 * 4 + 0] += xv[i] * w.x;
                    acc[i][j4 * 4 + 1] += xv[i] * w.y;
                    acc[i][j4 * 4 + 2] += xv[i] * w.z;
                    acc[i][j4 * 4 + 3] += xv[i] * w.w;
                }
            }
        }
    }
    for (int i = 0; i < 4; i++) {
        int gn = node0 + ng * 4 + i;
        if (gn < N_NODES) {
            for (int j4 = 0; j4 < 4; j4++) {
                ushort4 v;
                v.x = f2bf(fmaxf(acc[i][j4 * 4 + 0], 0.f));
                v.y = f2bf(fmaxf(acc[i][j4 * 4 + 1], 0.f));
                v.z = f2bf(fmaxf(acc[i][j4 * 4 + 2], 0.f));
                v.w = f2bf(fmaxf(acc[i][j4 * 4 + 3], 0.f));
                *(ushort4*)&h1b[gn * HID_DIM + o * 16 + j4 * 4] = v;
            }
        }
    }
}

// ---------------- layer2 transform GEMM (MFMA bf16, all etypes fused) ----------
// Block = 64 nodes, 4 waves; wave w owns rows w*16..w*16+15. A staged once,
// W2^T (pre-transposed bf16 table) staged per etype. Tiles padded to ASTR=136
// ushorts: fragment ds_read_b128 is exactly bank-uniform (r6 fix).
__global__ __launch_bounds__(256) void gemm2_k(const unsigned short* __restrict__ h1b,
                                               const unsigned short* __restrict__ w2tb,
                                               unsigned short* __restrict__ t2b) {
    __shared__ unsigned short As[64 * ASTR];   // 17.4 KB [node][k]
    __shared__ unsigned short Wt[64 * ASTR];   // 17.4 KB [n][k]
    int t = threadIdx.x;
    int node0 = blockIdx.x * 64;
    int w = t >> 6, lane = t & 63;
    int m = lane & 15, quad = lane >> 4;

    for (int j = t; j < 64 * 32; j += 256) {
        int n = j >> 5, c4 = (j & 31) * 4;
        int gn = node0 + n;
        int cn = gn < N_NODES ? gn : N_NODES - 1;
        *(ushort4*)&As[n * ASTR + c4] = *(const ushort4*)&h1b[cn * HID_DIM + c4];
    }
    __syncthreads();
    bf16x8 a[4];
    for (int ks = 0; ks < 4; ks++)
        a[ks] = *(const bf16x8*)&As[(w * 16 + m) * ASTR + ks * 32 + quad * 8];

    for (int e = 0; e < N_ETYPES; e++) {
        __syncthreads();                               // protect Wt from prev readers
        for (int j = t; j < 64 * 32; j += 256) {
            int n = j >> 5, c4 = (j & 31) * 4;
            *(ushort4*)&Wt[n * ASTR + c4] =
                *(const ushort4*)&w2tb[(e * OUT_DIM + n) * HID_DIM + c4];
        }
        __syncthreads();
        unsigned short* out = t2b + (size_t)e * N_NODES * OUT_DIM;
        for (int nt = 0; nt < 4; nt++) {
            f32x4 c = {0.f, 0.f, 0.f, 0.f};
            for (int ks = 0; ks < 4; ks++) {
                bf16x8 b = *(const bf16x8*)&Wt[(nt * 16 + m) * ASTR + ks * 32 + quad * 8];
                c = __builtin_amdgcn_mfma_f32_16x16x32_bf16(a[ks], b, c, 0, 0, 0);
            }
            for (int r = 0; r < 4; r++) {
                int gn = node0 + w * 16 + quad * 4 + r;
                if (gn < N_NODES) out[gn * OUT_DIM + nt * 16 + m] = f2bf(c[r]);
            }
        }
    }
}

// ---------------- layer2 pull + per-graph pool, eighth-bucket blocks ----------
__global__ __launch_bounds__(256) void gather2_k(const int* __restrict__ noff,
                                                 const int* __restrict__ degn,
                                                 const float* __restrict__ inv,
                                                 const unsigned* __restrict__ csr,
                                                 const unsigned short* __restrict__ t2b,
                                                 const int* __restrict__ gid,
                                                 float* __restrict__ gsum) {
    __shared__ float4 red4[16 * 4 * 16];    // 16 KB: [ng][slot][lane]
    int b = blockIdx.x, qb = blockIdx.y, t = threadIdx.x;
    int lane = t & 15, ng = t >> 4;
    int nbase = b * 256 + qb * 32;
    int gbase = nbase < N_NODES ? nbase : N_NODES - 1;
    int g0 = gid[gbase];
    float4 sa0 = {0,0,0,0}, sa1 = {0,0,0,0}, sa2 = {0,0,0,0}, sa3 = {0,0,0,0};

    for (int pass = 0; pass < 2; pass++) {
        int n = nbase + pass * 16 + ng;
        if (n >= N_NODES) break;
        float4 f = {0,0,0,0};
        for (int e = 0; e < N_ETYPES; e++) {
            int idx = e * N_NODES + n;
            int st = noff[idx];
            int cnt = degn[idx];
            float iv = inv[idx];
            const unsigned short* base = t2b + (size_t)e * N_NODES * OUT_DIM;
            ushort4 sv = *(const ushort4*)&base[n * OUT_DIM + lane * 4];
            float ax = bf2f(sv.x), ay = bf2f(sv.y), az = bf2f(sv.z), aw = bf2f(sv.w);
            int k = 0;
            for (; k + 1 < cnt; k += 2) {
                int sA = csr[st + k];
                int sB = csr[st + k + 1];
                ushort4 vA = *(const ushort4*)&base[sA * OUT_DIM + lane * 4];
                ushort4 vB = *(const ushort4*)&base[sB * OUT_DIM + lane * 4];
                ax += bf2f(vA.x) + bf2f(vB.x);
                ay += bf2f(vA.y) + bf2f(vB.y);
                az += bf2f(vA.z) + bf2f(vB.z);
                aw += bf2f(vA.w) + bf2f(vB.w);
            }
            if (k < cnt) {
                int sA = csr[st + k];
                ushort4 vA = *(const ushort4*)&base[sA * OUT_DIM + lane * 4];
                ax += bf2f(vA.x); ay += bf2f(vA.y); az += bf2f(vA.z); aw += bf2f(vA.w);
            }
            f.x += iv * ax; f.y += iv * ay; f.z += iv * az; f.w += iv * aw;
        }
        int slot = gid[n] - g0;
        float m0 = (slot == 0) ? 1.f : 0.f;
        float m1 = (slot == 1) ? 1.f : 0.f;
        float m2 = (slot == 2) ? 1.f : 0.f;
        float m3 = (slot == 3) ? 1.f : 0.f;
        sa0.x += m0 * f.x; sa0.y += m0 * f.y; sa0.z += m0 * f.z; sa0.w += m0 * f.w;
        sa1.x += m1 * f.x; sa1.y += m1 * f.y; sa1.z += m1 * f.z; sa1.w += m1 * f.w;
        sa2.x += m2 * f.x; sa2.y += m2 * f.y; sa2.z += m2 * f.z; sa2.w += m2 * f.w;
        sa3.x += m3 * f.x; sa3.y += m3 * f.y; sa3.z += m3 * f.z; sa3.w += m3 * f.w;
        if (slot > 3) {                      // statistically never
            atomicAdd(&gsum[(g0 + slot) * 64 + lane * 4 + 0], f.x);
            atomicAdd(&gsum[(g0 + slot) * 64 + lane * 4 + 1], f.y);
            atomicAdd(&gsum[(g0 + slot) * 64 + lane * 4 + 2], f.z);
            atomicAdd(&gsum[(g0 + slot) * 64 + lane * 4 + 3], f.w);
        }
    }
    red4[(ng * 4 + 0) * 16 + lane] = sa0;
    red4[(ng * 4 + 1) * 16 + lane] = sa1;
    red4[(ng * 4 + 2) * 16 + lane] = sa2;
    red4[(ng * 4 + 3) * 16 + lane] = sa3;
    __syncthreads();
    const float* red = (const float*)red4;
    int slot = t >> 6, d = t & 63;
    float s = 0.f;
    for (int j = 0; j < 16; j++) s += red[(j * 4 + slot) * 64 + d];
    int g = g0 + slot;
    if (g < NUM_GRAPHS) atomicAdd(&gsum[g * 64 + d], s);
}

// ---------------- per-graph node counts ----------------
__global__ __launch_bounds__(256) void gcnt_k(const int* __restrict__ gid,
                                              float* __restrict__ gcnt) {
    __shared__ int h[NUM_GRAPHS];
    int b = blockIdx.x, t = threadIdx.x;
    if (t < NUM_GRAPHS) h[t] = 0;
    __syncthreads();
    int n = b * 256 + t;
    if (n < N_NODES) atomicAdd(&h[gid[n]], 1);
    __syncthreads();
    if (t < NUM_GRAPHS && h[t] > 0) atomicAdd(&gcnt[t], (float)h[t]);
}

__global__ __launch_bounds__(256) void final_k(const float* __restrict__ gsum,
                                               const float* __restrict__ gcnt,
                                               const float* __restrict__ b2,
                                               float* __restrict__ out) {
    int idx = blockIdx.x * 256 + threadIdx.x;
    if (idx >= NUM_GRAPHS * OUT_DIM) return;
    int d = idx & 63;
    float B2 = 0.f;
    for (int e = 0; e < N_ETYPES; e++) B2 += b2[e * OUT_DIM + d];
    float c = gcnt[idx >> 6];
    out[idx] = (gsum[idx] + c * B2) / fmaxf(c, 1.0f);
}

extern "C" void kernel_launch(void* const* d_in, const int* in_sizes, int n_in,
                              void* d_out, int out_size, void* d_ws, size_t ws_size,
                              hipStream_t stream) {
    const float* feat = (const float*)d_in[0];
    const int*   src  = (const int*)d_in[1];
    const int*   dst  = (const int*)d_in[2];
    const int*   gid  = (const int*)d_in[3];
    const float* W1   = (const float*)d_in[4];
    const float* b1   = (const float*)d_in[5];
    const float* W2   = (const float*)d_in[6];
    const float* b2   = (const float*)d_in[7];

    float* ws = (float*)d_ws;
    int*            HP   = (int*)ws;                         //   244,375 (pad 245,000)
    int*            OFFP = (int*)ws + 245000;                //   244,375 (pad 245,000)
    int*            BSUM = (int*)ws + 490000;                //   512
    float*          INV  = ws + 490512;                      //   500,000
    int*            NOFF = (int*)ws + 990512;                //   500,000
    int*            DEGN = (int*)ws + 1490512;               //   500,000
    unsigned short* FB24 = (unsigned short*)(ws + 1990512);  //   2.4M bf16 = 1,200,000 f
    float*          GSUM = ws + 3190512;                     //   4,096
    float*          GCNT = ws + 3194608;                     //   64
    unsigned*       EP   = (unsigned*)(ws + 3195000);        //   4,000,000
    float*          AGG1 = ws + 7195000;                     //  12,000,000 (ends 19,195,000)
    unsigned short* T2B  = (unsigned short*)(ws + 3195000);  //  32M bf16 = 16,000,000 f
                    // T2B aliases EP (dead after sort_k) + AGG1 (dead after gemm1_k)
    unsigned short* H1B  = (unsigned short*)(ws + 19195000); //  12.8M bf16 = 6,400,000 f
    unsigned*       CSR  = (unsigned*)(ws + 25595000);       //   4,000,000
    unsigned short* W2TB = (unsigned short*)(ws + 29595000); //  40,960 bf16 = 20,480 f
    // total 29,615,480 floats = 118.5 MB

    hipMemsetAsync(GSUM, 0, (size_t)(4096 + 64) * sizeof(float), stream);

    cvt_feat_k<<<(N_NODES * FPAD + 255) / 256, 256, 0, stream>>>(feat, FB24);
    cvt_w2t_k<<<(N_ETYPES * OUT_DIM * HID_DIM + 255) / 256, 256, 0, stream>>>(W2, W2TB);
    part1_k<<<dim3(PBLK, N_ETYPES), 256, 0, stream>>>(dst, HP);
    scan1_k<<<SCAN_NBLK, 256, 0, stream>>>(HP, OFFP, BSUM);
    scan2_k<<<1, 256, 0, stream>>>(BSUM);
    scan3_k<<<(PN + 255) / 256, 256, 0, stream>>>(OFFP, BSUM);
    part2_k<<<dim3(PBLK, N_ETYPES), 256, 0, stream>>>(src, dst, OFFP, EP);
    sort_k<<<dim3(NBKT, N_ETYPES), 256, 0, stream>>>(OFFP, EP, CSR, NOFF, DEGN, INV);

    agg1_k<<<dim3(6250, N_ETYPES), 256, 0, stream>>>(NOFF, DEGN, CSR, FB24, INV, AGG1);
    gemm1_k<<<782, 256, 0, stream>>>(feat, AGG1, INV, W1, b1, H1B);
    gemm2_k<<<(N_NODES + 63) / 64, 256, 0, stream>>>(H1B, W2TB, T2B);
    gather2_k<<<dim3(NBKT, 8), 256, 0, stream>>>(NOFF, DEGN, INV, CSR, T2B, gid, GSUM);

    gcnt_k<<<391, 256, 0, stream>>>(gid, GCNT);
    final_k<<<16, 256, 0, stream>>>(GSUM, GCNT, b2, (float*)d_out);
}

// Round 8
// 531.737 us; speedup vs baseline: 1.2675x; 1.0798x over previous
//
#include <hip/hip_runtime.h>

#define N_NODES   100000
#define N_EDGES   800000
#define N_ETYPES  5
#define IN_DIM    23
#define FPAD      24                    // feat dims padded to 24 (48 B bf16 rows)
#define HID_DIM   128
#define OUT_DIM   64
#define NUM_GRAPHS 64
#define NBKT      391                   // ceil(100000/256) dst buckets of 256 nodes
#define PBLK      125                   // partition blocks per etype
#define CHUNK     6400                  // edges per partition block (125*6400 = 800000)
#define PN        (N_ETYPES*NBKT*PBLK)  // 244,375 histogram entries
#define SCAN_NBLK ((PN + 1023) / 1024)  // 239
#define TOT_EDGES (N_ETYPES*N_EDGES)    // 4,000,000
#define BKT_CAP   3072                  // max edges per (etype,bucket); mean 2048, sigma 45
#define ASTR      136                   // LDS tile stride: 128+8 ushorts = 272 B -> conflict-free

// NOTE (measured r3): bulk LDS float atomics ~3.5 cyc/lane on gfx950 — pull-gather only.
// NOTE (measured r4/r5): L3 row-gather needs >=1500 blocks for occupancy/latency hiding.
// NOTE (measured r6): unpadded [node][128] bf16 LDS tiles -> 16-way bank conflicts on MFMA
// fragment ds_read_b128; ASTR=136 fixes (1.47e7 -> ~0 SQ_LDS_BANK_CONFLICT).
// NOTE (measured r7): etype-interleaved gather over 64 MB bf16 T2B -> 92% L2 miss
// (FETCH 470 MB @ 3.4 TB/s = the whole dur). This round: fp8 rows + etype-outer loop
// to shrink live working set under the 4 MB/XCD L2.

__device__ __forceinline__ unsigned short f2bf(float x) {
    unsigned u = __float_as_uint(x);
    unsigned r = (u + 0x7FFFu + ((u >> 16) & 1u)) >> 16;   // RNE
    return (unsigned short)r;
}
__device__ __forceinline__ float bf2f(unsigned short h) {
    return __uint_as_float(((unsigned)h) << 16);
}

typedef __attribute__((ext_vector_type(8))) short bf16x8;
typedef __attribute__((ext_vector_type(4))) float f32x4;
typedef __attribute__((ext_vector_type(2))) float f32x2;

// ---------------- feat -> bf16 table, padded to 24 dims ----------------
__global__ __launch_bounds__(256) void cvt_feat_k(const float* __restrict__ feat,
                                                  unsigned short* __restrict__ fb24) {
    int i = blockIdx.x * 256 + threadIdx.x;
    if (i < N_NODES * FPAD) {
        int n = i / FPAD, d = i - n * FPAD;
        fb24[i] = (d < IN_DIM) ? f2bf(feat[n * IN_DIM + d]) : (unsigned short)0;
    }
}

// ---------------- W2 -> bf16 transposed table: w2tb[e][n][k] ----------------
__global__ __launch_bounds__(256) void cvt_w2t_k(const float* __restrict__ W2,
                                                 unsigned short* __restrict__ w2tb) {
    int i = blockIdx.x * 256 + threadIdx.x;
    if (i < N_ETYPES * OUT_DIM * HID_DIM) {
        int e = i / (OUT_DIM * HID_DIM);
        int r = i - e * (OUT_DIM * HID_DIM);
        int n = r >> 7, k = r & 127;
        w2tb[i] = f2bf(W2[(e * HID_DIM + k) * OUT_DIM + n]);
    }
}

// ---------------- partition pass 1: per-block bucket histogram ----------------
__global__ __launch_bounds__(256) void part1_k(const int* __restrict__ dst,
                                               int* __restrict__ hp) {
    __shared__ int hist[NBKT];
    int e = blockIdx.y, blk = blockIdx.x, t = threadIdx.x;
    for (int b = t; b < NBKT; b += 256) hist[b] = 0;
    __syncthreads();
    const int* dp = dst + e * N_EDGES + blk * CHUNK;
    for (int k = t; k < CHUNK; k += 256) atomicAdd(&hist[dp[k] >> 8], 1);
    __syncthreads();
    for (int b = t; b < NBKT; b += 256) hp[(e * NBKT + b) * PBLK + blk] = hist[b];
}

// ---------------- exclusive scan over 244,375 ----------------
__global__ __launch_bounds__(256) void scan1_k(const int* __restrict__ in,
                                               int* __restrict__ out,
                                               int* __restrict__ bsum) {
    __shared__ int ls[256];
    int t = threadIdx.x;
    int base = blockIdx.x * 1024 + t * 4;
    int v[4]; int s = 0;
    for (int j = 0; j < 4; j++) { int i = base + j; v[j] = (i < PN) ? in[i] : 0; s += v[j]; }
    ls[t] = s; __syncthreads();
    for (int o = 1; o < 256; o <<= 1) {
        int x = (t >= o) ? ls[t - o] : 0;
        __syncthreads();
        ls[t] += x;
        __syncthreads();
    }
    int run = (t > 0) ? ls[t - 1] : 0;
    if (t == 255) bsum[blockIdx.x] = ls[255];
    for (int j = 0; j < 4; j++) { int i = base + j; if (i < PN) out[i] = run; run += v[j]; }
}

__global__ __launch_bounds__(256) void scan2_k(int* __restrict__ bsum) {
    __shared__ int ls[256];
    int t = threadIdx.x;
    int v = (t < SCAN_NBLK) ? bsum[t] : 0;
    ls[t] = v; __syncthreads();
    for (int o = 1; o < 256; o <<= 1) {
        int x = (t >= o) ? ls[t - o] : 0;
        __syncthreads();
        ls[t] += x;
        __syncthreads();
    }
    if (t < SCAN_NBLK) bsum[t] = (t > 0) ? ls[t - 1] : 0;
}

__global__ __launch_bounds__(256) void scan3_k(int* __restrict__ off,
                                               const int* __restrict__ bsum) {
    int i = blockIdx.x * 256 + threadIdx.x;
    if (i < PN) off[i] += bsum[i >> 10];
}

// ---------------- partition pass 2: blocked contiguous scatter ----------------
__global__ __launch_bounds__(256) void part2_k(const int* __restrict__ src,
                                               const int* __restrict__ dst,
                                               const int* __restrict__ off,
                                               unsigned* __restrict__ ep) {
    __shared__ int cur[NBKT];
    int e = blockIdx.y, blk = blockIdx.x, t = threadIdx.x;
    for (int b = t; b < NBKT; b += 256) cur[b] = off[(e * NBKT + b) * PBLK + blk];
    __syncthreads();
    const int* dp = dst + e * N_EDGES + blk * CHUNK;
    const int* sp = src + e * N_EDGES + blk * CHUNK;
    for (int k = t; k < CHUNK; k += 256) {
        int d = dp[k], s = sp[k];
        int b = d >> 8;
        int pos = atomicAdd(&cur[b], 1);
        ep[pos] = (unsigned)s | ((unsigned)(d & 255) << 24);
    }
}

// ---------------- per-bucket counting sort -> node-sorted CSR + NOFF/DEG/INV ---
__global__ __launch_bounds__(256) void sort_k(const int* __restrict__ off,
                                              const unsigned* __restrict__ ep,
                                              unsigned* __restrict__ csr,
                                              int* __restrict__ noff,
                                              int* __restrict__ degn,
                                              float* __restrict__ inv) {
    __shared__ unsigned recs[BKT_CAP];
    __shared__ int hist[256];
    __shared__ int scn[256];
    __shared__ int curp[256];
    int b = blockIdx.x, e = blockIdx.y, t = threadIdx.x;
    int lin = (e * NBKT + b) * PBLK;
    int S = off[lin];
    int E = (lin == PN - PBLK) ? TOT_EDGES : off[lin + PBLK];
    int cnt = E - S;
    hist[t] = 0;
    __syncthreads();
    for (int i = t; i < cnt; i += 256) {
        unsigned r = ep[S + i];
        recs[i] = r;
        atomicAdd(&hist[r >> 24], 1);
    }
    __syncthreads();
    scn[t] = hist[t];
    __syncthreads();
    for (int o = 1; o < 256; o <<= 1) {
        int x = (t >= o) ? scn[t - o] : 0;
        __syncthreads();
        scn[t] += x;
        __syncthreads();
    }
    int excl = scn[t] - hist[t];
    curp[t] = excl;
    int n = b * 256 + t;
    if (n < N_NODES) {
        noff[e * N_NODES + n] = S + excl;
        degn[e * N_NODES + n] = hist[t];
        inv[e * N_NODES + n]  = 1.f / (float)(hist[t] + 1);
    }
    __syncthreads();
    for (int i = t; i < cnt; i += 256) {
        unsigned r = recs[i];
        int pos = atomicAdd(&curp[r >> 24], 1);
        csr[S + pos] = r & 0xFFFFFFu;
    }
}

// ---------------- layer1 pull-aggregate: AGG1[e,n,0:24] = inv * sum fb24[src] ----
__global__ __launch_bounds__(256) void agg1_k(const int* __restrict__ noff,
                                              const int* __restrict__ degn,
                                              const unsigned* __restrict__ csr,
                                              const unsigned short* __restrict__ fb24,
                                              const float* __restrict__ inv,
                                              float* __restrict__ agg1) {
    int e = blockIdx.y;
    int t = threadIdx.x;
    int lane = t & 15;
    int n = blockIdx.x * 16 + (t >> 4);
    int idx = e * N_NODES + n;
    if (lane >= 12) return;
    int st = noff[idx];
    int cnt = degn[idx];
    float a0 = 0.f, a1 = 0.f;
    int k = 0;
    for (; k + 1 < cnt; k += 2) {
        int s0 = csr[st + k];
        int s1 = csr[st + k + 1];
        ushort2 v0 = *(const ushort2*)&fb24[s0 * FPAD + lane * 2];
        ushort2 v1 = *(const ushort2*)&fb24[s1 * FPAD + lane * 2];
        a0 += bf2f(v0.x) + bf2f(v1.x);
        a1 += bf2f(v0.y) + bf2f(v1.y);
    }
    if (k < cnt) {
        int s0 = csr[st + k];
        ushort2 v0 = *(const ushort2*)&fb24[s0 * FPAD + lane * 2];
        a0 += bf2f(v0.x);
        a1 += bf2f(v0.y);
    }
    float iv = inv[idx];
    float2 o; o.x = a0 * iv; o.y = a1 * iv;
    *(float2*)&agg1[(size_t)idx * FPAD + lane * 2] = o;
}

// ---------------- layer1 GEMM -> H1 (bf16 out); AGG1 has stride 24 ----------------
__global__ __launch_bounds__(256) void gemm1_k(const float* __restrict__ feat,
                                               const float* __restrict__ agg1,
                                               const float* __restrict__ inv,
                                               const float* __restrict__ W1,
                                               const float* __restrict__ b1,
                                               unsigned short* __restrict__ h1b) {
    __shared__ float xs[128 * 25];
    __shared__ float wl[IN_DIM * HID_DIM];
    int t = threadIdx.x;
    int node0 = blockIdx.x * 128;
    int ng = t >> 3;
    int o  = t & 7;
    float acc[4][16];
    for (int i = 0; i < 4; i++)
        for (int j = 0; j < 16; j++) acc[i][j] = 0.f;

    for (int e = 0; e < N_ETYPES; e++) {
        __syncthreads();
        for (int j = t; j < IN_DIM * HID_DIM; j += 256)
            wl[j] = W1[e * IN_DIM * HID_DIM + j];
        for (int j = t; j < 128 * IN_DIM; j += 256) {
            int nl = j / IN_DIM;
            int k  = j - nl * IN_DIM;
            int gn = node0 + nl;
            int cn = gn < N_NODES ? gn : N_NODES - 1;
            xs[nl * 25 + k] = agg1[(size_t)(e * N_NODES + cn) * FPAD + k]
                            + feat[cn * IN_DIM + k] * inv[e * N_NODES + cn];
        }
        __syncthreads();
        for (int j = 0; j < 16; j++) {
            float bb = b1[e * HID_DIM + o * 16 + j];
            for (int i = 0; i < 4; i++) acc[i][j] += bb;
        }
        for (int k = 0; k < IN_DIM; k++) {
            float xv[4];
            for (int i = 0; i < 4; i++) xv[i] = xs[(ng * 4 + i) * 25 + k];
            for (int j4 = 0; j4 < 4; j4++) {
                float4 w = *(const float4*)&wl[k * HID_DIM + o * 16 + j4 * 4];
                for (int i = 0; i < 4; i++) {
                    acc[i][j4 * 4 + 0] += xv[i] * w.x;
                    acc[i][j4 * 4 + 1] += xv[i] * w.y;
                    acc[i][j4 * 4 + 2] += xv[i] * w.z;
                    acc[i][j4 * 4 + 3] += xv[i] * w.w;
                }
            }
        }
    }
    for (int i = 0; i < 4; i++) {
        int gn = node0 + ng * 4 + i;
        if (gn < N_NODES) {
            for (int j4 = 0; j4 < 4; j4++) {
                ushort4 v;
                v.x = f2bf(fmaxf(acc[i][j4 * 4 + 0], 0.f));
                v.y = f2bf(fmaxf(acc[i][j4 * 4 + 1], 0.f));
                v.z = f2bf(fmaxf(acc[i][j4 * 4 + 2], 0.f));
                v.w = f2bf(fmaxf(acc[i][j4 * 4 + 3], 0.f));
                *(ushort4*)&h1b[gn * HID_DIM + o * 16 + j4 * 4] = v;
            }
        }
    }
}

// ---------------- layer2 transform GEMM (MFMA bf16 -> fp8 out) ----------
// Block = 64 nodes, 4 waves. A staged once, W2^T per etype. ASTR padding (r6).
// Epilogue quantizes to OCP fp8-e4m3 (1 B/elem): halves the gather payload.
__global__ __launch_bounds__(256) void gemm2_k(const unsigned short* __restrict__ h1b,
                                               const unsigned short* __restrict__ w2tb,
                                               unsigned char* __restrict__ t2f8) {
    __shared__ unsigned short As[64 * ASTR];   // 17.4 KB [node][k]
    __shared__ unsigned short Wt[64 * ASTR];   // 17.4 KB [n][k]
    int t = threadIdx.x;
    int node0 = blockIdx.x * 64;
    int w = t >> 6, lane = t & 63;
    int m = lane & 15, quad = lane >> 4;

    for (int j = t; j < 64 * 32; j += 256) {
        int n = j >> 5, c4 = (j & 31) * 4;
        int gn = node0 + n;
        int cn = gn < N_NODES ? gn : N_NODES - 1;
        *(ushort4*)&As[n * ASTR + c4] = *(const ushort4*)&h1b[cn * HID_DIM + c4];
    }
    __syncthreads();
    bf16x8 a[4];
    for (int ks = 0; ks < 4; ks++)
        a[ks] = *(const bf16x8*)&As[(w * 16 + m) * ASTR + ks * 32 + quad * 8];

    for (int e = 0; e < N_ETYPES; e++) {
        __syncthreads();                               // protect Wt from prev readers
        for (int j = t; j < 64 * 32; j += 256) {
            int n = j >> 5, c4 = (j & 31) * 4;
            *(ushort4*)&Wt[n * ASTR + c4] =
                *(const ushort4*)&w2tb[(e * OUT_DIM + n) * HID_DIM + c4];
        }
        __syncthreads();
        unsigned char* out = t2f8 + (size_t)e * N_NODES * OUT_DIM;
        for (int nt = 0; nt < 4; nt++) {
            f32x4 c = {0.f, 0.f, 0.f, 0.f};
            for (int ks = 0; ks < 4; ks++) {
                bf16x8 b = *(const bf16x8*)&Wt[(nt * 16 + m) * ASTR + ks * 32 + quad * 8];
                c = __builtin_amdgcn_mfma_f32_16x16x32_bf16(a[ks], b, c, 0, 0, 0);
            }
            for (int r = 0; r < 4; r++) {
                int gn = node0 + w * 16 + quad * 4 + r;
                if (gn < N_NODES) {
                    int p = __builtin_amdgcn_cvt_pk_fp8_f32(c[r], c[r], 0, false);
                    out[(size_t)gn * OUT_DIM + nt * 16 + m] = (unsigned char)(p & 0xFF);
                }
            }
        }
    }
}

// ---------------- layer2 pull + per-graph pool; ETYPE-OUTERMOST, fp8 rows -------
// grid (NBKT, 8): block = 32 nodes. 16 groups x 16 lanes; lane reads 4 fp8 (uint).
// e outer so the live gather working set is one 6.4 MB table (L2-resident-ish).
__global__ __launch_bounds__(256) void gather2_k(const int* __restrict__ noff,
                                                 const int* __restrict__ degn,
                                                 const float* __restrict__ inv,
                                                 const unsigned* __restrict__ csr,
                                                 const unsigned char* __restrict__ t2f8,
                                                 const int* __restrict__ gid,
                                                 float* __restrict__ gsum) {
    __shared__ float4 red4[16 * 4 * 16];    // 16 KB: [ng][slot][lane]
    int b = blockIdx.x, qb = blockIdx.y, t = threadIdx.x;
    int lane = t & 15, ng = t >> 4;
    int nbase = b * 256 + qb * 32;
    int gbase = nbase < N_NODES ? nbase : N_NODES - 1;
    int g0 = gid[gbase];
    float4 f[2];
    f[0] = make_float4(0.f, 0.f, 0.f, 0.f);
    f[1] = make_float4(0.f, 0.f, 0.f, 0.f);

    for (int e = 0; e < N_ETYPES; e++) {
        const unsigned char* base = t2f8 + (size_t)e * N_NODES * OUT_DIM;
        #pragma unroll
        for (int pass = 0; pass < 2; pass++) {
            int n = nbase + pass * 16 + ng;
            if (n >= N_NODES) break;
            int idx = e * N_NODES + n;
            int st = noff[idx];
            int cnt = degn[idx];
            float iv = inv[idx];
            unsigned rv = *(const unsigned*)&base[(size_t)n * OUT_DIM + lane * 4];
            f32x2 lo = __builtin_amdgcn_cvt_pk_f32_fp8((int)rv, false);
            f32x2 hi = __builtin_amdgcn_cvt_pk_f32_fp8((int)rv, true);
            float ax = lo.x, ay = lo.y, az = hi.x, aw = hi.y;
            int k = 0;
            for (; k + 1 < cnt; k += 2) {
                int sA = csr[st + k];
                int sB = csr[st + k + 1];
                unsigned rA = *(const unsigned*)&base[(size_t)sA * OUT_DIM + lane * 4];
                unsigned rB = *(const unsigned*)&base[(size_t)sB * OUT_DIM + lane * 4];
                f32x2 lA = __builtin_amdgcn_cvt_pk_f32_fp8((int)rA, false);
                f32x2 hA = __builtin_amdgcn_cvt_pk_f32_fp8((int)rA, true);
                f32x2 lB = __builtin_amdgcn_cvt_pk_f32_fp8((int)rB, false);
                f32x2 hB = __builtin_amdgcn_cvt_pk_f32_fp8((int)rB, true);
                ax += lA.x + lB.x; ay += lA.y + lB.y;
                az += hA.x + hB.x; aw += hA.y + hB.y;
            }
            if (k < cnt) {
                int sA = csr[st + k];
                unsigned rA = *(const unsigned*)&base[(size_t)sA * OUT_DIM + lane * 4];
                f32x2 lA = __builtin_amdgcn_cvt_pk_f32_fp8((int)rA, false);
                f32x2 hA = __builtin_amdgcn_cvt_pk_f32_fp8((int)rA, true);
                ax += lA.x; ay += lA.y; az += hA.x; aw += hA.y;
            }
            f[pass].x += iv * ax; f[pass].y += iv * ay;
            f[pass].z += iv * az; f[pass].w += iv * aw;
        }
    }

    float4 sa0 = {0,0,0,0}, sa1 = {0,0,0,0}, sa2 = {0,0,0,0}, sa3 = {0,0,0,0};
    #pragma unroll
    for (int pass = 0; pass < 2; pass++) {
        int n = nbase + pass * 16 + ng;
        if (n >= N_NODES) break;
        float4 v = f[pass];
        int slot = gid[n] - g0;
        float m0 = (slot == 0) ? 1.f : 0.f;
        float m1 = (slot == 1) ? 1.f : 0.f;
        float m2 = (slot == 2) ? 1.f : 0.f;
        float m3 = (slot == 3) ? 1.f : 0.f;
        sa0.x += m0 * v.x; sa0.y += m0 * v.y; sa0.z += m0 * v.z; sa0.w += m0 * v.w;
        sa1.x += m1 * v.x; sa1.y += m1 * v.y; sa1.z += m1 * v.z; sa1.w += m1 * v.w;
        sa2.x += m2 * v.x; sa2.y += m2 * v.y; sa2.z += m2 * v.z; sa2.w += m2 * v.w;
        sa3.x += m3 * v.x; sa3.y += m3 * v.y; sa3.z += m3 * v.z; sa3.w += m3 * v.w;
        if (slot > 3) {                      // statistically never
            atomicAdd(&gsum[(g0 + slot) * 64 + lane * 4 + 0], v.x);
            atomicAdd(&gsum[(g0 + slot) * 64 + lane * 4 + 1], v.y);
            atomicAdd(&gsum[(g0 + slot) * 64 + lane * 4 + 2], v.z);
            atomicAdd(&gsum[(g0 + slot) * 64 + lane * 4 + 3], v.w);
        }
    }
    red4[(ng * 4 + 0) * 16 + lane] = sa0;
    red4[(ng * 4 + 1) * 16 + lane] = sa1;
    red4[(ng * 4 + 2) * 16 + lane] = sa2;
    red4[(ng * 4 + 3) * 16 + lane] = sa3;
    __syncthreads();
    const float* red = (const float*)red4;
    int slot = t >> 6, d = t & 63;
    float s = 0.f;
    for (int j = 0; j < 16; j++) s += red[(j * 4 + slot) * 64 + d];
    int g = g0 + slot;
    if (g < NUM_GRAPHS) atomicAdd(&gsum[g * 64 + d], s);
}

// ---------------- per-graph node counts ----------------
__global__ __launch_bounds__(256) void gcnt_k(const int* __restrict__ gid,
                                              float* __restrict__ gcnt) {
    __shared__ int h[NUM_GRAPHS];
    int b = blockIdx.x, t = threadIdx.x;
    if (t < NUM_GRAPHS) h[t] = 0;
    __syncthreads();
    int n = b * 256 + t;
    if (n < N_NODES) atomicAdd(&h[gid[n]], 1);
    __syncthreads();
    if (t < NUM_GRAPHS && h[t] > 0) atomicAdd(&gcnt[t], (float)h[t]);
}

__global__ __launch_bounds__(256) void final_k(const float* __restrict__ gsum,
                                               const float* __restrict__ gcnt,
                                               const float* __restrict__ b2,
                                               float* __restrict__ out) {
    int idx = blockIdx.x * 256 + threadIdx.x;
    if (idx >= NUM_GRAPHS * OUT_DIM) return;
    int d = idx & 63;
    float B2 = 0.f;
    for (int e = 0; e < N_ETYPES; e++) B2 += b2[e * OUT_DIM + d];
    float c = gcnt[idx >> 6];
    out[idx] = (gsum[idx] + c * B2) / fmaxf(c, 1.0f);
}

extern "C" void kernel_launch(void* const* d_in, const int* in_sizes, int n_in,
                              void* d_out, int out_size, void* d_ws, size_t ws_size,
                              hipStream_t stream) {
    const float* feat = (const float*)d_in[0];
    const int*   src  = (const int*)d_in[1];
    const int*   dst  = (const int*)d_in[2];
    const int*   gid  = (const int*)d_in[3];
    const float* W1   = (const float*)d_in[4];
    const float* b1   = (const float*)d_in[5];
    const float* W2   = (const float*)d_in[6];
    const float* b2   = (const float*)d_in[7];

    float* ws = (float*)d_ws;
    int*            HP   = (int*)ws;                         //   244,375 (pad 245,000)
    int*            OFFP = (int*)ws + 245000;                //   244,375 (pad 245,000)
    int*            BSUM = (int*)ws + 490000;                //   512
    float*          INV  = ws + 490512;                      //   500,000
    int*            NOFF = (int*)ws + 990512;                //   500,000
    int*            DEGN = (int*)ws + 1490512;               //   500,000
    unsigned short* FB24 = (unsigned short*)(ws + 1990512);  //   2.4M bf16 = 1,200,000 f
    float*          GSUM = ws + 3190512;                     //   4,096
    float*          GCNT = ws + 3194608;                     //   64
    unsigned*       EP   = (unsigned*)(ws + 3195000);        //   4,000,000
    float*          AGG1 = ws + 7195000;                     //  12,000,000 (ends 19,195,000)
    unsigned char*  T2F8 = (unsigned char*)(ws + 3195000);   //  32 MB fp8 = 8,000,000 f
                    // T2F8 aliases EP (dead after sort_k) + AGG1[0:4M] (dead after gemm1_k)
    unsigned short* H1B  = (unsigned short*)(ws + 19195000); //  12.8M bf16 = 6,400,000 f
    unsigned*       CSR  = (unsigned*)(ws + 25595000);       //   4,000,000
    unsigned short* W2TB = (unsigned short*)(ws + 29595000); //  40,960 bf16 = 20,480 f
    // total 29,615,480 floats = 118.5 MB

    hipMemsetAsync(GSUM, 0, (size_t)(4096 + 64) * sizeof(float), stream);

    cvt_feat_k<<<(N_NODES * FPAD + 255) / 256, 256, 0, stream>>>(feat, FB24);
    cvt_w2t_k<<<(N_ETYPES * OUT_DIM * HID_DIM + 255) / 256, 256, 0, stream>>>(W2, W2TB);
    part1_k<<<dim3(PBLK, N_ETYPES), 256, 0, stream>>>(dst, HP);
    scan1_k<<<SCAN_NBLK, 256, 0, stream>>>(HP, OFFP, BSUM);
    scan2_k<<<1, 256, 0, stream>>>(BSUM);
    scan3_k<<<(PN + 255) / 256, 256, 0, stream>>>(OFFP, BSUM);
    part2_k<<<dim3(PBLK, N_ETYPES), 256, 0, stream>>>(src, dst, OFFP, EP);
    sort_k<<<dim3(NBKT, N_ETYPES), 256, 0, stream>>>(OFFP, EP, CSR, NOFF, DEGN, INV);

    agg1_k<<<dim3(6250, N_ETYPES), 256, 0, stream>>>(NOFF, DEGN, CSR, FB24, INV, AGG1);
    gemm1_k<<<782, 256, 0, stream>>>(feat, AGG1, INV, W1, b1, H1B);
    gemm2_k<<<(N_NODES + 63) / 64, 256, 0, stream>>>(H1B, W2TB, T2F8);
    gather2_k<<<dim3(NBKT, 8), 256, 0, stream>>>(NOFF, DEGN, INV, CSR, T2F8, gid, GSUM);

    gcnt_k<<<391, 256, 0, stream>>>(gid, GCNT);
    final_k<<<16, 256, 0, stream>>>(GSUM, GCNT, b2, (float*)d_out);
}

// Round 9
// 439.401 us; speedup vs baseline: 1.5339x; 1.2101x over previous
//
#include <hip/hip_runtime.h>

#define N_NODES   100000
#define N_EDGES   800000
#define N_ETYPES  5
#define IN_DIM    23
#define FPAD      24                    // feat dims padded to 24 (48 B bf16 rows)
#define HID_DIM   128
#define OUT_DIM   64
#define NUM_GRAPHS 64
#define NBKT      391                   // ceil(100000/256) dst buckets of 256 nodes
#define PBLK      125                   // partition blocks per etype
#define CHUNK     6400                  // edges per partition block (125*6400 = 800000)
#define PN        (N_ETYPES*NBKT*PBLK)  // 244,375 histogram entries
#define SCAN_NBLK ((PN + 1023) / 1024)  // 239
#define TOT_EDGES (N_ETYPES*N_EDGES)    // 4,000,000
#define BKT_CAP   3072                  // max edges per (etype,bucket); mean 2048, sigma 45
#define ASTR      136                   // gemm2 LDS stride: 128+8 ushorts -> conflict-free
#define A1STR     40                    // gemm1 LDS stride: 32+8 ushorts -> 2-way only (free)

// NOTE (measured r3): bulk LDS float atomics ~3.5 cyc/lane on gfx950 — pull-gather only.
// NOTE (measured r4/r5): L3 row-gather needs >=1500 blocks for occupancy/latency hiding.
// NOTE (measured r6): unpadded bf16 LDS tiles -> 16-way conflicts on MFMA ds_read_b128;
// pad stride so (bank = addr/4 % 32) is uniform across the (m,quad) lane map.
// NOTE (measured r7): etype-interleaved gather over 64 MB bf16 -> 92% L2 miss; fixed r8
// with fp8 rows + etype-outer loop (FETCH 470->~150 MB).
// NOTE (measured r8): fp32-VALU gemm1 was LDS-bound w/ 4-way conflicts on the W tile
// (6.1e6 SQ_LDS_BANK_CONFLICT) at 18.7% occupancy -> ported to MFMA (this round).

__device__ __forceinline__ unsigned short f2bf(float x) {
    unsigned u = __float_as_uint(x);
    unsigned r = (u + 0x7FFFu + ((u >> 16) & 1u)) >> 16;   // RNE
    return (unsigned short)r;
}
__device__ __forceinline__ float bf2f(unsigned short h) {
    return __uint_as_float(((unsigned)h) << 16);
}

typedef __attribute__((ext_vector_type(8))) short bf16x8;
typedef __attribute__((ext_vector_type(4))) float f32x4;
typedef __attribute__((ext_vector_type(2))) float f32x2;

// ---------------- feat -> bf16 table, padded to 24 dims ----------------
__global__ __launch_bounds__(256) void cvt_feat_k(const float* __restrict__ feat,
                                                  unsigned short* __restrict__ fb24) {
    int i = blockIdx.x * 256 + threadIdx.x;
    if (i < N_NODES * FPAD) {
        int n = i / FPAD, d = i - n * FPAD;
        fb24[i] = (d < IN_DIM) ? f2bf(feat[n * IN_DIM + d]) : (unsigned short)0;
    }
}

// ---------------- W2 -> bf16 transposed table: w2tb[e][n][k] ----------------
__global__ __launch_bounds__(256) void cvt_w2t_k(const float* __restrict__ W2,
                                                 unsigned short* __restrict__ w2tb) {
    int i = blockIdx.x * 256 + threadIdx.x;
    if (i < N_ETYPES * OUT_DIM * HID_DIM) {
        int e = i / (OUT_DIM * HID_DIM);
        int r = i - e * (OUT_DIM * HID_DIM);
        int n = r >> 7, k = r & 127;
        w2tb[i] = f2bf(W2[(e * HID_DIM + k) * OUT_DIM + n]);
    }
}

// ---------------- W1 -> bf16 transposed table: w1tb[e][n(128)][k(32, zero-pad)] ----
__global__ __launch_bounds__(256) void cvt_w1t_k(const float* __restrict__ W1,
                                                 unsigned short* __restrict__ w1tb) {
    int i = blockIdx.x * 256 + threadIdx.x;
    if (i < N_ETYPES * HID_DIM * 32) {
        int e = i / (HID_DIM * 32);
        int r = i - e * (HID_DIM * 32);
        int n = r >> 5, k = r & 31;
        w1tb[i] = (k < IN_DIM) ? f2bf(W1[e * IN_DIM * HID_DIM + k * HID_DIM + n])
                               : (unsigned short)0;
    }
}

// ---------------- b1 summed over etypes ----------------
__global__ __launch_bounds__(128) void cvt_b1s_k(const float* __restrict__ b1,
                                                 float* __restrict__ b1s) {
    int d = threadIdx.x;
    float s = 0.f;
    for (int e = 0; e < N_ETYPES; e++) s += b1[e * HID_DIM + d];
    b1s[d] = s;
}

// ---------------- partition pass 1: per-block bucket histogram ----------------
__global__ __launch_bounds__(256) void part1_k(const int* __restrict__ dst,
                                               int* __restrict__ hp) {
    __shared__ int hist[NBKT];
    int e = blockIdx.y, blk = blockIdx.x, t = threadIdx.x;
    for (int b = t; b < NBKT; b += 256) hist[b] = 0;
    __syncthreads();
    const int* dp = dst + e * N_EDGES + blk * CHUNK;
    for (int k = t; k < CHUNK; k += 256) atomicAdd(&hist[dp[k] >> 8], 1);
    __syncthreads();
    for (int b = t; b < NBKT; b += 256) hp[(e * NBKT + b) * PBLK + blk] = hist[b];
}

// ---------------- exclusive scan over 244,375 ----------------
__global__ __launch_bounds__(256) void scan1_k(const int* __restrict__ in,
                                               int* __restrict__ out,
                                               int* __restrict__ bsum) {
    __shared__ int ls[256];
    int t = threadIdx.x;
    int base = blockIdx.x * 1024 + t * 4;
    int v[4]; int s = 0;
    for (int j = 0; j < 4; j++) { int i = base + j; v[j] = (i < PN) ? in[i] : 0; s += v[j]; }
    ls[t] = s; __syncthreads();
    for (int o = 1; o < 256; o <<= 1) {
        int x = (t >= o) ? ls[t - o] : 0;
        __syncthreads();
        ls[t] += x;
        __syncthreads();
    }
    int run = (t > 0) ? ls[t - 1] : 0;
    if (t == 255) bsum[blockIdx.x] = ls[255];
    for (int j = 0; j < 4; j++) { int i = base + j; if (i < PN) out[i] = run; run += v[j]; }
}

__global__ __launch_bounds__(256) void scan2_k(int* __restrict__ bsum) {
    __shared__ int ls[256];
    int t = threadIdx.x;
    int v = (t < SCAN_NBLK) ? bsum[t] : 0;
    ls[t] = v; __syncthreads();
    for (int o = 1; o < 256; o <<= 1) {
        int x = (t >= o) ? ls[t - o] : 0;
        __syncthreads();
        ls[t] += x;
        __syncthreads();
    }
    if (t < SCAN_NBLK) bsum[t] = (t > 0) ? ls[t - 1] : 0;
}

__global__ __launch_bounds__(256) void scan3_k(int* __restrict__ off,
                                               const int* __restrict__ bsum) {
    int i = blockIdx.x * 256 + threadIdx.x;
    if (i < PN) off[i] += bsum[i >> 10];
}

// ---------------- partition pass 2: blocked contiguous scatter ----------------
__global__ __launch_bounds__(256) void part2_k(const int* __restrict__ src,
                                               const int* __restrict__ dst,
                                               const int* __restrict__ off,
                                               unsigned* __restrict__ ep) {
    __shared__ int cur[NBKT];
    int e = blockIdx.y, blk = blockIdx.x, t = threadIdx.x;
    for (int b = t; b < NBKT; b += 256) cur[b] = off[(e * NBKT + b) * PBLK + blk];
    __syncthreads();
    const int* dp = dst + e * N_EDGES + blk * CHUNK;
    const int* sp = src + e * N_EDGES + blk * CHUNK;
    for (int k = t; k < CHUNK; k += 256) {
        int d = dp[k], s = sp[k];
        int b = d >> 8;
        int pos = atomicAdd(&cur[b], 1);
        ep[pos] = (unsigned)s | ((unsigned)(d & 255) << 24);
    }
}

// ---------------- per-bucket counting sort -> node-sorted CSR + NOFF/DEG/INV ---
__global__ __launch_bounds__(256) void sort_k(const int* __restrict__ off,
                                              const unsigned* __restrict__ ep,
                                              unsigned* __restrict__ csr,
                                              int* __restrict__ noff,
                                              int* __restrict__ degn,
                                              float* __restrict__ inv) {
    __shared__ unsigned recs[BKT_CAP];
    __shared__ int hist[256];
    __shared__ int scn[256];
    __shared__ int curp[256];
    int b = blockIdx.x, e = blockIdx.y, t = threadIdx.x;
    int lin = (e * NBKT + b) * PBLK;
    int S = off[lin];
    int E = (lin == PN - PBLK) ? TOT_EDGES : off[lin + PBLK];
    int cnt = E - S;
    hist[t] = 0;
    __syncthreads();
    for (int i = t; i < cnt; i += 256) {
        unsigned r = ep[S + i];
        recs[i] = r;
        atomicAdd(&hist[r >> 24], 1);
    }
    __syncthreads();
    scn[t] = hist[t];
    __syncthreads();
    for (int o = 1; o < 256; o <<= 1) {
        int x = (t >= o) ? scn[t - o] : 0;
        __syncthreads();
        scn[t] += x;
        __syncthreads();
    }
    int excl = scn[t] - hist[t];
    curp[t] = excl;
    int n = b * 256 + t;
    if (n < N_NODES) {
        noff[e * N_NODES + n] = S + excl;
        degn[e * N_NODES + n] = hist[t];
        inv[e * N_NODES + n]  = 1.f / (float)(hist[t] + 1);
    }
    __syncthreads();
    for (int i = t; i < cnt; i += 256) {
        unsigned r = recs[i];
        int pos = atomicAdd(&curp[r >> 24], 1);
        csr[S + pos] = r & 0xFFFFFFu;
    }
}

// ---------------- layer1 pull-aggregate (self-term folded in, bf16 out) --------
// AGG1B[e,n,0:32] = bf16( inv * (sum_{j->n} fb24[j] + fb24[n]) ), cols 24..31 zero.
__global__ __launch_bounds__(256) void agg1_k(const int* __restrict__ noff,
                                              const int* __restrict__ degn,
                                              const unsigned* __restrict__ csr,
                                              const unsigned short* __restrict__ fb24,
                                              const float* __restrict__ inv,
                                              unsigned short* __restrict__ agg1b) {
    int e = blockIdx.y;
    int t = threadIdx.x;
    int lane = t & 15;
    int n = blockIdx.x * 16 + (t >> 4);
    int idx = e * N_NODES + n;
    if (lane >= 12) {                      // zero-pad cols 24..31
        ushort2 z; z.x = 0; z.y = 0;
        *(ushort2*)&agg1b[(size_t)idx * 32 + lane * 2] = z;
        return;
    }
    int st = noff[idx];
    int cnt = degn[idx];
    ushort2 sv = *(const ushort2*)&fb24[n * FPAD + lane * 2];   // self term
    float a0 = bf2f(sv.x), a1 = bf2f(sv.y);
    int k = 0;
    for (; k + 1 < cnt; k += 2) {
        int s0 = csr[st + k];
        int s1 = csr[st + k + 1];
        ushort2 v0 = *(const ushort2*)&fb24[s0 * FPAD + lane * 2];
        ushort2 v1 = *(const ushort2*)&fb24[s1 * FPAD + lane * 2];
        a0 += bf2f(v0.x) + bf2f(v1.x);
        a1 += bf2f(v0.y) + bf2f(v1.y);
    }
    if (k < cnt) {
        int s0 = csr[st + k];
        ushort2 v0 = *(const ushort2*)&fb24[s0 * FPAD + lane * 2];
        a0 += bf2f(v0.x);
        a1 += bf2f(v0.y);
    }
    float iv = inv[idx];
    ushort2 o; o.x = f2bf(a0 * iv); o.y = f2bf(a1 * iv);
    *(ushort2*)&agg1b[(size_t)idx * 32 + lane * 2] = o;
}

// ---------------- layer1 GEMM (MFMA bf16): H1 = relu(sum_e AGG1B_e @ W1_e + B1) ---
// Block = 64 nodes, 4 waves; K=32 single MFMA step; 8 output tiles of 16 dims.
// LDS stride A1STR=40 ushorts -> only free 2-way bank aliasing on fragment reads.
__global__ __launch_bounds__(256) void gemm1_k(const unsigned short* __restrict__ agg1b,
                                               const unsigned short* __restrict__ w1tb,
                                               const float* __restrict__ b1s,
                                               unsigned short* __restrict__ h1b) {
    __shared__ unsigned short As[64 * A1STR];    // 5.1 KB [node][k]
    __shared__ unsigned short Wt[128 * A1STR];   // 10.2 KB [n][k]
    int t = threadIdx.x;
    int node0 = blockIdx.x * 64;
    int w = t >> 6, lane = t & 63;
    int m = lane & 15, quad = lane >> 4;

    f32x4 acc[8];
    for (int nt = 0; nt < 8; nt++) {
        float bb = b1s[nt * 16 + m];
        f32x4 c = {bb, bb, bb, bb};
        acc[nt] = c;
    }

    for (int e = 0; e < N_ETYPES; e++) {
        __syncthreads();
        for (int j = t; j < 64 * 8; j += 256) {       // 512 ushort4
            int n = j >> 3, c4 = (j & 7) * 4;
            int gn = node0 + n;
            int cn = gn < N_NODES ? gn : N_NODES - 1;
            *(ushort4*)&As[n * A1STR + c4] =
                *(const ushort4*)&agg1b[(size_t)(e * N_NODES + cn) * 32 + c4];
        }
        for (int j = t; j < 128 * 8; j += 256) {      // 1024 ushort4
            int n = j >> 3, c4 = (j & 7) * 4;
            *(ushort4*)&Wt[n * A1STR + c4] =
                *(const ushort4*)&w1tb[(size_t)(e * HID_DIM + n) * 32 + c4];
        }
        __syncthreads();
        bf16x8 a = *(const bf16x8*)&As[(w * 16 + m) * A1STR + quad * 8];
        for (int nt = 0; nt < 8; nt++) {
            bf16x8 b = *(const bf16x8*)&Wt[(nt * 16 + m) * A1STR + quad * 8];
            acc[nt] = __builtin_amdgcn_mfma_f32_16x16x32_bf16(a, b, acc[nt], 0, 0, 0);
        }
    }
    for (int nt = 0; nt < 8; nt++) {
        for (int r = 0; r < 4; r++) {
            int gn = node0 + w * 16 + quad * 4 + r;
            if (gn < N_NODES)
                h1b[(size_t)gn * HID_DIM + nt * 16 + m] = f2bf(fmaxf(acc[nt][r], 0.f));
        }
    }
}

// ---------------- layer2 transform GEMM (MFMA bf16 -> fp8 out) ----------
__global__ __launch_bounds__(256) void gemm2_k(const unsigned short* __restrict__ h1b,
                                               const unsigned short* __restrict__ w2tb,
                                               unsigned char* __restrict__ t2f8) {
    __shared__ unsigned short As[64 * ASTR];   // 17.4 KB [node][k]
    __shared__ unsigned short Wt[64 * ASTR];   // 17.4 KB [n][k]
    int t = threadIdx.x;
    int node0 = blockIdx.x * 64;
    int w = t >> 6, lane = t & 63;
    int m = lane & 15, quad = lane >> 4;

    for (int j = t; j < 64 * 32; j += 256) {
        int n = j >> 5, c4 = (j & 31) * 4;
        int gn = node0 + n;
        int cn = gn < N_NODES ? gn : N_NODES - 1;
        *(ushort4*)&As[n * ASTR + c4] = *(const ushort4*)&h1b[cn * HID_DIM + c4];
    }
    __syncthreads();
    bf16x8 a[4];
    for (int ks = 0; ks < 4; ks++)
        a[ks] = *(const bf16x8*)&As[(w * 16 + m) * ASTR + ks * 32 + quad * 8];

    for (int e = 0; e < N_ETYPES; e++) {
        __syncthreads();                               // protect Wt from prev readers
        for (int j = t; j < 64 * 32; j += 256) {
            int n = j >> 5, c4 = (j & 31) * 4;
            *(ushort4*)&Wt[n * ASTR + c4] =
                *(const ushort4*)&w2tb[(e * OUT_DIM + n) * HID_DIM + c4];
        }
        __syncthreads();
        unsigned char* out = t2f8 + (size_t)e * N_NODES * OUT_DIM;
        for (int nt = 0; nt < 4; nt++) {
            f32x4 c = {0.f, 0.f, 0.f, 0.f};
            for (int ks = 0; ks < 4; ks++) {
                bf16x8 b = *(const bf16x8*)&Wt[(nt * 16 + m) * ASTR + ks * 32 + quad * 8];
                c = __builtin_amdgcn_mfma_f32_16x16x32_bf16(a[ks], b, c, 0, 0, 0);
            }
            for (int r = 0; r < 4; r++) {
                int gn = node0 + w * 16 + quad * 4 + r;
                if (gn < N_NODES) {
                    int p = __builtin_amdgcn_cvt_pk_fp8_f32(c[r], c[r], 0, false);
                    out[(size_t)gn * OUT_DIM + nt * 16 + m] = (unsigned char)(p & 0xFF);
                }
            }
        }
    }
}

// ---------------- layer2 pull + per-graph pool; ETYPE-OUTERMOST, fp8 rows -------
__global__ __launch_bounds__(256) void gather2_k(const int* __restrict__ noff,
                                                 const int* __restrict__ degn,
                                                 const float* __restrict__ inv,
                                                 const unsigned* __restrict__ csr,
                                                 const unsigned char* __restrict__ t2f8,
                                                 const int* __restrict__ gid,
                                                 float* __restrict__ gsum) {
    __shared__ float4 red4[16 * 4 * 16];    // 16 KB: [ng][slot][lane]
    int b = blockIdx.x, qb = blockIdx.y, t = threadIdx.x;
    int lane = t & 15, ng = t >> 4;
    int nbase = b * 256 + qb * 32;
    int gbase = nbase < N_NODES ? nbase : N_NODES - 1;
    int g0 = gid[gbase];
    float4 f[2];
    f[0] = make_float4(0.f, 0.f, 0.f, 0.f);
    f[1] = make_float4(0.f, 0.f, 0.f, 0.f);

    for (int e = 0; e < N_ETYPES; e++) {
        const unsigned char* base = t2f8 + (size_t)e * N_NODES * OUT_DIM;
        #pragma unroll
        for (int pass = 0; pass < 2; pass++) {
            int n = nbase + pass * 16 + ng;
            if (n >= N_NODES) break;
            int idx = e * N_NODES + n;
            int st = noff[idx];
            int cnt = degn[idx];
            float iv = inv[idx];
            unsigned rv = *(const unsigned*)&base[(size_t)n * OUT_DIM + lane * 4];
            f32x2 lo = __builtin_amdgcn_cvt_pk_f32_fp8((int)rv, false);
            f32x2 hi = __builtin_amdgcn_cvt_pk_f32_fp8((int)rv, true);
            float ax = lo.x, ay = lo.y, az = hi.x, aw = hi.y;
            int k = 0;
            for (; k + 1 < cnt; k += 2) {
                int sA = csr[st + k];
                int sB = csr[st + k + 1];
                unsigned rA = *(const unsigned*)&base[(size_t)sA * OUT_DIM + lane * 4];
                unsigned rB = *(const unsigned*)&base[(size_t)sB * OUT_DIM + lane * 4];
                f32x2 lA = __builtin_amdgcn_cvt_pk_f32_fp8((int)rA, false);
                f32x2 hA = __builtin_amdgcn_cvt_pk_f32_fp8((int)rA, true);
                f32x2 lB = __builtin_amdgcn_cvt_pk_f32_fp8((int)rB, false);
                f32x2 hB = __builtin_amdgcn_cvt_pk_f32_fp8((int)rB, true);
                ax += lA.x + lB.x; ay += lA.y + lB.y;
                az += hA.x + hB.x; aw += hA.y + hB.y;
            }
            if (k < cnt) {
                int sA = csr[st + k];
                unsigned rA = *(const unsigned*)&base[(size_t)sA * OUT_DIM + lane * 4];
                f32x2 lA = __builtin_amdgcn_cvt_pk_f32_fp8((int)rA, false);
                f32x2 hA = __builtin_amdgcn_cvt_pk_f32_fp8((int)rA, true);
                ax += lA.x; ay += lA.y; az += hA.x; aw += hA.y;
            }
            f[pass].x += iv * ax; f[pass].y += iv * ay;
            f[pass].z += iv * az; f[pass].w += iv * aw;
        }
    }

    float4 sa0 = {0,0,0,0}, sa1 = {0,0,0,0}, sa2 = {0,0,0,0}, sa3 = {0,0,0,0};
    #pragma unroll
    for (int pass = 0; pass < 2; pass++) {
        int n = nbase + pass * 16 + ng;
        if (n >= N_NODES) break;
        float4 v = f[pass];
        int slot = gid[n] - g0;
        float m0 = (slot == 0) ? 1.f : 0.f;
        float m1 = (slot == 1) ? 1.f : 0.f;
        float m2 = (slot == 2) ? 1.f : 0.f;
        float m3 = (slot == 3) ? 1.f : 0.f;
        sa0.x += m0 * v.x; sa0.y += m0 * v.y; sa0.z += m0 * v.z; sa0.w += m0 * v.w;
        sa1.x += m1 * v.x; sa1.y += m1 * v.y; sa1.z += m1 * v.z; sa1.w += m1 * v.w;
        sa2.x += m2 * v.x; sa2.y += m2 * v.y; sa2.z += m2 * v.z; sa2.w += m2 * v.w;
        sa3.x += m3 * v.x; sa3.y += m3 * v.y; sa3.z += m3 * v.z; sa3.w += m3 * v.w;
        if (slot > 3) {                      // statistically never
            atomicAdd(&gsum[(g0 + slot) * 64 + lane * 4 + 0], v.x);
            atomicAdd(&gsum[(g0 + slot) * 64 + lane * 4 + 1], v.y);
            atomicAdd(&gsum[(g0 + slot) * 64 + lane * 4 + 2], v.z);
            atomicAdd(&gsum[(g0 + slot) * 64 + lane * 4 + 3], v.w);
        }
    }
    red4[(ng * 4 + 0) * 16 + lane] = sa0;
    red4[(ng * 4 + 1) * 16 + lane] = sa1;
    red4[(ng * 4 + 2) * 16 + lane] = sa2;
    red4[(ng * 4 + 3) * 16 + lane] = sa3;
    __syncthreads();
    const float* red = (const float*)red4;
    int slot = t >> 6, d = t & 63;
    float s = 0.f;
    for (int j = 0; j < 16; j++) s += red[(j * 4 + slot) * 64 + d];
    int g = g0 + slot;
    if (g < NUM_GRAPHS) atomicAdd(&gsum[g * 64 + d], s);
}

// ---------------- per-graph node counts ----------------
__global__ __launch_bounds__(256) void gcnt_k(const int* __restrict__ gid,
                                              float* __restrict__ gcnt) {
    __shared__ int h[NUM_GRAPHS];
    int b = blockIdx.x, t = threadIdx.x;
    if (t < NUM_GRAPHS) h[t] = 0;
    __syncthreads();
    int n = b * 256 + t;
    if (n < N_NODES) atomicAdd(&h[gid[n]], 1);
    __syncthreads();
    if (t < NUM_GRAPHS && h[t] > 0) atomicAdd(&gcnt[t], (float)h[t]);
}

__global__ __launch_bounds__(256) void final_k(const float* __restrict__ gsum,
                                               const float* __restrict__ gcnt,
                                               const float* __restrict__ b2,
                                               float* __restrict__ out) {
    int idx = blockIdx.x * 256 + threadIdx.x;
    if (idx >= NUM_GRAPHS * OUT_DIM) return;
    int d = idx & 63;
    float B2 = 0.f;
    for (int e = 0; e < N_ETYPES; e++) B2 += b2[e * OUT_DIM + d];
    float c = gcnt[idx >> 6];
    out[idx] = (gsum[idx] + c * B2) / fmaxf(c, 1.0f);
}

extern "C" void kernel_launch(void* const* d_in, const int* in_sizes, int n_in,
                              void* d_out, int out_size, void* d_ws, size_t ws_size,
                              hipStream_t stream) {
    const float* feat = (const float*)d_in[0];
    const int*   src  = (const int*)d_in[1];
    const int*   dst  = (const int*)d_in[2];
    const int*   gid  = (const int*)d_in[3];
    const float* W1   = (const float*)d_in[4];
    const float* b1   = (const float*)d_in[5];
    const float* W2   = (const float*)d_in[6];
    const float* b2   = (const float*)d_in[7];

    float* ws = (float*)d_ws;
    int*            HP   = (int*)ws;                         //   244,375 (pad 245,000)
    int*            OFFP = (int*)ws + 245000;                //   244,375 (pad 245,000)
    int*            BSUM = (int*)ws + 490000;                //   512
    float*          INV  = ws + 490512;                      //   500,000
    int*            NOFF = (int*)ws + 990512;                //   500,000
    int*            DEGN = (int*)ws + 1490512;               //   500,000
    unsigned short* FB24 = (unsigned short*)(ws + 1990512);  //   2.4M bf16 = 1,200,000 f
    float*          GSUM = ws + 3190512;                     //   4,096
    float*          GCNT = ws + 3194608;                     //   64
    unsigned*       EP   = (unsigned*)(ws + 3195000);        //   4,000,000
    unsigned short* AGG1B= (unsigned short*)(ws + 7195000);  //  16M bf16 = 8,000,000 f
                    // (written by agg1_k after sort_k; dead after gemm1_k)
    unsigned char*  T2F8 = (unsigned char*)(ws + 3195000);   //  32 MB fp8 = 8,000,000 f
                    // T2F8 aliases EP (dead after sort_k) + AGG1B[0:16MB] (dead after gemm1)
    unsigned short* H1B  = (unsigned short*)(ws + 19195000); //  12.8M bf16 = 6,400,000 f
    unsigned*       CSR  = (unsigned*)(ws + 25595000);       //   4,000,000
    unsigned short* W2TB = (unsigned short*)(ws + 29595000); //  40,960 bf16 = 20,480 f
    unsigned short* W1TB = (unsigned short*)(ws + 29615480); //  20,480 bf16 = 10,240 f
    float*          B1S  = ws + 29625720;                    //   128
    // total 29,625,848 floats = 118.5 MB

    hipMemsetAsync(GSUM, 0, (size_t)(4096 + 64) * sizeof(float), stream);

    cvt_feat_k<<<(N_NODES * FPAD + 255) / 256, 256, 0, stream>>>(feat, FB24);
    cvt_w2t_k<<<(N_ETYPES * OUT_DIM * HID_DIM + 255) / 256, 256, 0, stream>>>(W2, W2TB);
    cvt_w1t_k<<<(N_ETYPES * HID_DIM * 32 + 255) / 256, 256, 0, stream>>>(W1, W1TB);
    cvt_b1s_k<<<1, 128, 0, stream>>>(b1, B1S);
    part1_k<<<dim3(PBLK, N_ETYPES), 256, 0, stream>>>(dst, HP);
    scan1_k<<<SCAN_NBLK, 256, 0, stream>>>(HP, OFFP, BSUM);
    scan2_k<<<1, 256, 0, stream>>>(BSUM);
    scan3_k<<<(PN + 255) / 256, 256, 0, stream>>>(OFFP, BSUM);
    part2_k<<<dim3(PBLK, N_ETYPES), 256, 0, stream>>>(src, dst, OFFP, EP);
    sort_k<<<dim3(NBKT, N_ETYPES), 256, 0, stream>>>(OFFP, EP, CSR, NOFF, DEGN, INV);

    agg1_k<<<dim3(6250, N_ETYPES), 256, 0, stream>>>(NOFF, DEGN, CSR, FB24, INV, AGG1B);
    gemm1_k<<<(N_NODES + 63) / 64, 256, 0, stream>>>(AGG1B, W1TB, B1S, H1B);
    gemm2_k<<<(N_NODES + 63) / 64, 256, 0, stream>>>(H1B, W2TB, T2F8);
    gather2_k<<<dim3(NBKT, 8), 256, 0, stream>>>(NOFF, DEGN, INV, CSR, T2F8, gid, GSUM);

    gcnt_k<<<391, 256, 0, stream>>>(gid, GCNT);
    final_k<<<16, 256, 0, stream>>>(GSUM, GCNT, b2, (float*)d_out);
}

// Round 10
// 424.825 us; speedup vs baseline: 1.5865x; 1.0343x over previous
//
#include <hip/hip_runtime.h>

#define N_NODES   100000
#define N_EDGES   800000
#define N_ETYPES  5
#define IN_DIM    23
#define FPAD      32                    // feat dims padded to 32 (64 B bf16 rows = 1 line)
#define HID_DIM   128
#define OUT_DIM   64
#define NUM_GRAPHS 64
#define NBKT      391                   // ceil(100000/256) dst buckets of 256 nodes
#define PBLK      125                   // partition blocks per etype
#define CHUNK     6400                  // edges per partition block (125*6400 = 800000)
#define PN        (N_ETYPES*NBKT*PBLK)  // 244,375 histogram entries
#define SCAN_NBLK ((PN + 1023) / 1024)  // 239
#define TOT_EDGES (N_ETYPES*N_EDGES)    // 4,000,000
#define BKT_CAP   3072                  // max edges per (etype,bucket); mean 2048, sigma 45
#define ASTR      136                   // gemm2 LDS stride: 128+8 ushorts -> conflict-free
#define A1STR     40                    // gemm1 LDS stride: 32+8 ushorts -> 2-way only (free)

// NOTE (measured r3): bulk LDS float atomics ~3.5 cyc/lane on gfx950 — pull-gather only.
// NOTE (measured r4/r5): L3 row-gather needs >=1500 blocks for occupancy/latency hiding.
// NOTE (measured r6): unpadded bf16 LDS tiles -> 16-way conflicts on MFMA ds_read_b128;
// pad stride so (bank = addr/4 % 32) is uniform across the (m,quad) lane map.
// NOTE (measured r7/r8): etype-interleaved gather over 64 MB bf16 -> 92% L2 miss; fp8
// rows + etype-outer loop halved FETCH (470->252 MB).
// NOTE (measured r8): fp32-VALU gemm1 was LDS-conflict-bound -> MFMA port (r9) fixed.
// NOTE (measured r9): fp8 gather became miss-LATENCY bound (BW 3.4->2.4 TB/s when bytes
// halved). This round: 64 B-aligned feat rows (FPAD 32) + unroll-4 for 2x rows in flight.

__device__ __forceinline__ unsigned short f2bf(float x) {
    unsigned u = __float_as_uint(x);
    unsigned r = (u + 0x7FFFu + ((u >> 16) & 1u)) >> 16;   // RNE
    return (unsigned short)r;
}
__device__ __forceinline__ float bf2f(unsigned short h) {
    return __uint_as_float(((unsigned)h) << 16);
}

typedef __attribute__((ext_vector_type(8))) short bf16x8;
typedef __attribute__((ext_vector_type(4))) float f32x4;
typedef __attribute__((ext_vector_type(2))) float f32x2;

// ---------------- feat -> bf16 table, padded to 32 dims (one line/row) ----------
__global__ __launch_bounds__(256) void cvt_feat_k(const float* __restrict__ feat,
                                                  unsigned short* __restrict__ fb32) {
    int i = blockIdx.x * 256 + threadIdx.x;
    if (i < N_NODES * FPAD) {
        int n = i >> 5, d = i & 31;
        fb32[i] = (d < IN_DIM) ? f2bf(feat[n * IN_DIM + d]) : (unsigned short)0;
    }
}

// ---------------- W2 -> bf16 transposed table: w2tb[e][n][k] ----------------
__global__ __launch_bounds__(256) void cvt_w2t_k(const float* __restrict__ W2,
                                                 unsigned short* __restrict__ w2tb) {
    int i = blockIdx.x * 256 + threadIdx.x;
    if (i < N_ETYPES * OUT_DIM * HID_DIM) {
        int e = i / (OUT_DIM * HID_DIM);
        int r = i - e * (OUT_DIM * HID_DIM);
        int n = r >> 7, k = r & 127;
        w2tb[i] = f2bf(W2[(e * HID_DIM + k) * OUT_DIM + n]);
    }
}

// ---------------- W1 -> bf16 transposed table: w1tb[e][n(128)][k(32, zero-pad)] ----
__global__ __launch_bounds__(256) void cvt_w1t_k(const float* __restrict__ W1,
                                                 unsigned short* __restrict__ w1tb) {
    int i = blockIdx.x * 256 + threadIdx.x;
    if (i < N_ETYPES * HID_DIM * 32) {
        int e = i / (HID_DIM * 32);
        int r = i - e * (HID_DIM * 32);
        int n = r >> 5, k = r & 31;
        w1tb[i] = (k < IN_DIM) ? f2bf(W1[e * IN_DIM * HID_DIM + k * HID_DIM + n])
                               : (unsigned short)0;
    }
}

// ---------------- b1 summed over etypes ----------------
__global__ __launch_bounds__(128) void cvt_b1s_k(const float* __restrict__ b1,
                                                 float* __restrict__ b1s) {
    int d = threadIdx.x;
    float s = 0.f;
    for (int e = 0; e < N_ETYPES; e++) s += b1[e * HID_DIM + d];
    b1s[d] = s;
}

// ---------------- partition pass 1: per-block bucket histogram ----------------
__global__ __launch_bounds__(256) void part1_k(const int* __restrict__ dst,
                                               int* __restrict__ hp) {
    __shared__ int hist[NBKT];
    int e = blockIdx.y, blk = blockIdx.x, t = threadIdx.x;
    for (int b = t; b < NBKT; b += 256) hist[b] = 0;
    __syncthreads();
    const int* dp = dst + e * N_EDGES + blk * CHUNK;
    for (int k = t; k < CHUNK; k += 256) atomicAdd(&hist[dp[k] >> 8], 1);
    __syncthreads();
    for (int b = t; b < NBKT; b += 256) hp[(e * NBKT + b) * PBLK + blk] = hist[b];
}

// ---------------- exclusive scan over 244,375 ----------------
__global__ __launch_bounds__(256) void scan1_k(const int* __restrict__ in,
                                               int* __restrict__ out,
                                               int* __restrict__ bsum) {
    __shared__ int ls[256];
    int t = threadIdx.x;
    int base = blockIdx.x * 1024 + t * 4;
    int v[4]; int s = 0;
    for (int j = 0; j < 4; j++) { int i = base + j; v[j] = (i < PN) ? in[i] : 0; s += v[j]; }
    ls[t] = s; __syncthreads();
    for (int o = 1; o < 256; o <<= 1) {
        int x = (t >= o) ? ls[t - o] : 0;
        __syncthreads();
        ls[t] += x;
        __syncthreads();
    }
    int run = (t > 0) ? ls[t - 1] : 0;
    if (t == 255) bsum[blockIdx.x] = ls[255];
    for (int j = 0; j < 4; j++) { int i = base + j; if (i < PN) out[i] = run; run += v[j]; }
}

__global__ __launch_bounds__(256) void scan2_k(int* __restrict__ bsum) {
    __shared__ int ls[256];
    int t = threadIdx.x;
    int v = (t < SCAN_NBLK) ? bsum[t] : 0;
    ls[t] = v; __syncthreads();
    for (int o = 1; o < 256; o <<= 1) {
        int x = (t >= o) ? ls[t - o] : 0;
        __syncthreads();
        ls[t] += x;
        __syncthreads();
    }
    if (t < SCAN_NBLK) bsum[t] = (t > 0) ? ls[t - 1] : 0;
}

__global__ __launch_bounds__(256) void scan3_k(int* __restrict__ off,
                                               const int* __restrict__ bsum) {
    int i = blockIdx.x * 256 + threadIdx.x;
    if (i < PN) off[i] += bsum[i >> 10];
}

// ---------------- partition pass 2: blocked contiguous scatter ----------------
__global__ __launch_bounds__(256) void part2_k(const int* __restrict__ src,
                                               const int* __restrict__ dst,
                                               const int* __restrict__ off,
                                               unsigned* __restrict__ ep) {
    __shared__ int cur[NBKT];
    int e = blockIdx.y, blk = blockIdx.x, t = threadIdx.x;
    for (int b = t; b < NBKT; b += 256) cur[b] = off[(e * NBKT + b) * PBLK + blk];
    __syncthreads();
    const int* dp = dst + e * N_EDGES + blk * CHUNK;
    const int* sp = src + e * N_EDGES + blk * CHUNK;
    for (int k = t; k < CHUNK; k += 256) {
        int d = dp[k], s = sp[k];
        int b = d >> 8;
        int pos = atomicAdd(&cur[b], 1);
        ep[pos] = (unsigned)s | ((unsigned)(d & 255) << 24);
    }
}

// ---------------- per-bucket counting sort -> node-sorted CSR + NOFF/DEG/INV ---
__global__ __launch_bounds__(256) void sort_k(const int* __restrict__ off,
                                              const unsigned* __restrict__ ep,
                                              unsigned* __restrict__ csr,
                                              int* __restrict__ noff,
                                              int* __restrict__ degn,
                                              float* __restrict__ inv) {
    __shared__ unsigned recs[BKT_CAP];
    __shared__ int hist[256];
    __shared__ int scn[256];
    __shared__ int curp[256];
    int b = blockIdx.x, e = blockIdx.y, t = threadIdx.x;
    int lin = (e * NBKT + b) * PBLK;
    int S = off[lin];
    int E = (lin == PN - PBLK) ? TOT_EDGES : off[lin + PBLK];
    int cnt = E - S;
    hist[t] = 0;
    __syncthreads();
    for (int i = t; i < cnt; i += 256) {
        unsigned r = ep[S + i];
        recs[i] = r;
        atomicAdd(&hist[r >> 24], 1);
    }
    __syncthreads();
    scn[t] = hist[t];
    __syncthreads();
    for (int o = 1; o < 256; o <<= 1) {
        int x = (t >= o) ? scn[t - o] : 0;
        __syncthreads();
        scn[t] += x;
        __syncthreads();
    }
    int excl = scn[t] - hist[t];
    curp[t] = excl;
    int n = b * 256 + t;
    if (n < N_NODES) {
        noff[e * N_NODES + n] = S + excl;
        degn[e * N_NODES + n] = hist[t];
        inv[e * N_NODES + n]  = 1.f / (float)(hist[t] + 1);
    }
    __syncthreads();
    for (int i = t; i < cnt; i += 256) {
        unsigned r = recs[i];
        int pos = atomicAdd(&curp[r >> 24], 1);
        csr[S + pos] = r & 0xFFFFFFu;
    }
}

// ---------------- layer1 pull-aggregate (self-term folded in, bf16 out) --------
// AGG1B[e,n,0:32] = bf16( inv * (sum_{j->n} fb32[j] + fb32[n]) ); 16 lanes x ushort2,
// unroll-4 for 16 rows in flight per wave.
__global__ __launch_bounds__(256) void agg1_k(const int* __restrict__ noff,
                                              const int* __restrict__ degn,
                                              const unsigned* __restrict__ csr,
                                              const unsigned short* __restrict__ fb32,
                                              const float* __restrict__ inv,
                                              unsigned short* __restrict__ agg1b) {
    int e = blockIdx.y;
    int t = threadIdx.x;
    int lane = t & 15;
    int n = blockIdx.x * 16 + (t >> 4);
    int idx = e * N_NODES + n;
    int st = noff[idx];
    int cnt = degn[idx];
    ushort2 sv = *(const ushort2*)&fb32[n * FPAD + lane * 2];   // self term
    float a0 = bf2f(sv.x), a1 = bf2f(sv.y);
    int k = 0;
    for (; k + 3 < cnt; k += 4) {
        int s0 = csr[st + k];
        int s1 = csr[st + k + 1];
        int s2 = csr[st + k + 2];
        int s3 = csr[st + k + 3];
        ushort2 v0 = *(const ushort2*)&fb32[s0 * FPAD + lane * 2];
        ushort2 v1 = *(const ushort2*)&fb32[s1 * FPAD + lane * 2];
        ushort2 v2 = *(const ushort2*)&fb32[s2 * FPAD + lane * 2];
        ushort2 v3 = *(const ushort2*)&fb32[s3 * FPAD + lane * 2];
        a0 += bf2f(v0.x) + bf2f(v1.x) + bf2f(v2.x) + bf2f(v3.x);
        a1 += bf2f(v0.y) + bf2f(v1.y) + bf2f(v2.y) + bf2f(v3.y);
    }
    for (; k < cnt; k++) {
        int s0 = csr[st + k];
        ushort2 v0 = *(const ushort2*)&fb32[s0 * FPAD + lane * 2];
        a0 += bf2f(v0.x);
        a1 += bf2f(v0.y);
    }
    float iv = inv[idx];
    ushort2 o; o.x = f2bf(a0 * iv); o.y = f2bf(a1 * iv);
    *(ushort2*)&agg1b[(size_t)idx * 32 + lane * 2] = o;
}

// ---------------- layer1 GEMM (MFMA bf16): H1 = relu(sum_e AGG1B_e @ W1_e + B1) ---
__global__ __launch_bounds__(256) void gemm1_k(const unsigned short* __restrict__ agg1b,
                                               const unsigned short* __restrict__ w1tb,
                                               const float* __restrict__ b1s,
                                               unsigned short* __restrict__ h1b) {
    __shared__ unsigned short As[64 * A1STR];    // 5.1 KB [node][k]
    __shared__ unsigned short Wt[128 * A1STR];   // 10.2 KB [n][k]
    int t = threadIdx.x;
    int node0 = blockIdx.x * 64;
    int w = t >> 6, lane = t & 63;
    int m = lane & 15, quad = lane >> 4;

    f32x4 acc[8];
    for (int nt = 0; nt < 8; nt++) {
        float bb = b1s[nt * 16 + m];
        f32x4 c = {bb, bb, bb, bb};
        acc[nt] = c;
    }

    for (int e = 0; e < N_ETYPES; e++) {
        __syncthreads();
        for (int j = t; j < 64 * 8; j += 256) {       // 512 ushort4
            int n = j >> 3, c4 = (j & 7) * 4;
            int gn = node0 + n;
            int cn = gn < N_NODES ? gn : N_NODES - 1;
            *(ushort4*)&As[n * A1STR + c4] =
                *(const ushort4*)&agg1b[(size_t)(e * N_NODES + cn) * 32 + c4];
        }
        for (int j = t; j < 128 * 8; j += 256) {      // 1024 ushort4
            int n = j >> 3, c4 = (j & 7) * 4;
            *(ushort4*)&Wt[n * A1STR + c4] =
                *(const ushort4*)&w1tb[(size_t)(e * HID_DIM + n) * 32 + c4];
        }
        __syncthreads();
        bf16x8 a = *(const bf16x8*)&As[(w * 16 + m) * A1STR + quad * 8];
        for (int nt = 0; nt < 8; nt++) {
            bf16x8 b = *(const bf16x8*)&Wt[(nt * 16 + m) * A1STR + quad * 8];
            acc[nt] = __builtin_amdgcn_mfma_f32_16x16x32_bf16(a, b, acc[nt], 0, 0, 0);
        }
    }
    for (int nt = 0; nt < 8; nt++) {
        for (int r = 0; r < 4; r++) {
            int gn = node0 + w * 16 + quad * 4 + r;
            if (gn < N_NODES)
                h1b[(size_t)gn * HID_DIM + nt * 16 + m] = f2bf(fmaxf(acc[nt][r], 0.f));
        }
    }
}

// ---------------- layer2 transform GEMM (MFMA bf16 -> fp8 out) ----------
__global__ __launch_bounds__(256) void gemm2_k(const unsigned short* __restrict__ h1b,
                                               const unsigned short* __restrict__ w2tb,
                                               unsigned char* __restrict__ t2f8) {
    __shared__ unsigned short As[64 * ASTR];   // 17.4 KB [node][k]
    __shared__ unsigned short Wt[64 * ASTR];   // 17.4 KB [n][k]
    int t = threadIdx.x;
    int node0 = blockIdx.x * 64;
    int w = t >> 6, lane = t & 63;
    int m = lane & 15, quad = lane >> 4;

    for (int j = t; j < 64 * 32; j += 256) {
        int n = j >> 5, c4 = (j & 31) * 4;
        int gn = node0 + n;
        int cn = gn < N_NODES ? gn : N_NODES - 1;
        *(ushort4*)&As[n * ASTR + c4] = *(const ushort4*)&h1b[cn * HID_DIM + c4];
    }
    __syncthreads();
    bf16x8 a[4];
    for (int ks = 0; ks < 4; ks++)
        a[ks] = *(const bf16x8*)&As[(w * 16 + m) * ASTR + ks * 32 + quad * 8];

    for (int e = 0; e < N_ETYPES; e++) {
        __syncthreads();                               // protect Wt from prev readers
        for (int j = t; j < 64 * 32; j += 256) {
            int n = j >> 5, c4 = (j & 31) * 4;
            *(ushort4*)&Wt[n * ASTR + c4] =
                *(const ushort4*)&w2tb[(e * OUT_DIM + n) * HID_DIM + c4];
        }
        __syncthreads();
        unsigned char* out = t2f8 + (size_t)e * N_NODES * OUT_DIM;
        for (int nt = 0; nt < 4; nt++) {
            f32x4 c = {0.f, 0.f, 0.f, 0.f};
            for (int ks = 0; ks < 4; ks++) {
                bf16x8 b = *(const bf16x8*)&Wt[(nt * 16 + m) * ASTR + ks * 32 + quad * 8];
                c = __builtin_amdgcn_mfma_f32_16x16x32_bf16(a[ks], b, c, 0, 0, 0);
            }
            for (int r = 0; r < 4; r++) {
                int gn = node0 + w * 16 + quad * 4 + r;
                if (gn < N_NODES) {
                    int p = __builtin_amdgcn_cvt_pk_fp8_f32(c[r], c[r], 0, false);
                    out[(size_t)gn * OUT_DIM + nt * 16 + m] = (unsigned char)(p & 0xFF);
                }
            }
        }
    }
}

// ---------------- layer2 pull + per-graph pool; etype-outer, fp8, unroll-4 ------
__global__ __launch_bounds__(256) void gather2_k(const int* __restrict__ noff,
                                                 const int* __restrict__ degn,
                                                 const float* __restrict__ inv,
                                                 const unsigned* __restrict__ csr,
                                                 const unsigned char* __restrict__ t2f8,
                                                 const int* __restrict__ gid,
                                                 float* __restrict__ gsum) {
    __shared__ float4 red4[16 * 4 * 16];    // 16 KB: [ng][slot][lane]
    int b = blockIdx.x, qb = blockIdx.y, t = threadIdx.x;
    int lane = t & 15, ng = t >> 4;
    int nbase = b * 256 + qb * 32;
    int gbase = nbase < N_NODES ? nbase : N_NODES - 1;
    int g0 = gid[gbase];
    float4 f[2];
    f[0] = make_float4(0.f, 0.f, 0.f, 0.f);
    f[1] = make_float4(0.f, 0.f, 0.f, 0.f);

    for (int e = 0; e < N_ETYPES; e++) {
        const unsigned char* base = t2f8 + (size_t)e * N_NODES * OUT_DIM;
        #pragma unroll
        for (int pass = 0; pass < 2; pass++) {
            int n = nbase + pass * 16 + ng;
            if (n >= N_NODES) break;
            int idx = e * N_NODES + n;
            int st = noff[idx];
            int cnt = degn[idx];
            float iv = inv[idx];
            unsigned rv = *(const unsigned*)&base[(size_t)n * OUT_DIM + lane * 4];
            f32x2 lo = __builtin_amdgcn_cvt_pk_f32_fp8((int)rv, false);
            f32x2 hi = __builtin_amdgcn_cvt_pk_f32_fp8((int)rv, true);
            float ax = lo.x, ay = lo.y, az = hi.x, aw = hi.y;
            int k = 0;
            for (; k + 3 < cnt; k += 4) {
                int sA = csr[st + k];
                int sB = csr[st + k + 1];
                int sC = csr[st + k + 2];
                int sD = csr[st + k + 3];
                unsigned rA = *(const unsigned*)&base[(size_t)sA * OUT_DIM + lane * 4];
                unsigned rB = *(const unsigned*)&base[(size_t)sB * OUT_DIM + lane * 4];
                unsigned rC = *(const unsigned*)&base[(size_t)sC * OUT_DIM + lane * 4];
                unsigned rD = *(const unsigned*)&base[(size_t)sD * OUT_DIM + lane * 4];
                f32x2 lA = __builtin_amdgcn_cvt_pk_f32_fp8((int)rA, false);
                f32x2 hA = __builtin_amdgcn_cvt_pk_f32_fp8((int)rA, true);
                f32x2 lB = __builtin_amdgcn_cvt_pk_f32_fp8((int)rB, false);
                f32x2 hB = __builtin_amdgcn_cvt_pk_f32_fp8((int)rB, true);
                f32x2 lC = __builtin_amdgcn_cvt_pk_f32_fp8((int)rC, false);
                f32x2 hC = __builtin_amdgcn_cvt_pk_f32_fp8((int)rC, true);
                f32x2 lD = __builtin_amdgcn_cvt_pk_f32_fp8((int)rD, false);
                f32x2 hD = __builtin_amdgcn_cvt_pk_f32_fp8((int)rD, true);
                ax += (lA.x + lB.x) + (lC.x + lD.x);
                ay += (lA.y + lB.y) + (lC.y + lD.y);
                az += (hA.x + hB.x) + (hC.x + hD.x);
                aw += (hA.y + hB.y) + (hC.y + hD.y);
            }
            for (; k < cnt; k++) {
                int sA = csr[st + k];
                unsigned rA = *(const unsigned*)&base[(size_t)sA * OUT_DIM + lane * 4];
                f32x2 lA = __builtin_amdgcn_cvt_pk_f32_fp8((int)rA, false);
                f32x2 hA = __builtin_amdgcn_cvt_pk_f32_fp8((int)rA, true);
                ax += lA.x; ay += lA.y; az += hA.x; aw += hA.y;
            }
            f[pass].x += iv * ax; f[pass].y += iv * ay;
            f[pass].z += iv * az; f[pass].w += iv * aw;
        }
    }

    float4 sa0 = {0,0,0,0}, sa1 = {0,0,0,0}, sa2 = {0,0,0,0}, sa3 = {0,0,0,0};
    #pragma unroll
    for (int pass = 0; pass < 2; pass++) {
        int n = nbase + pass * 16 + ng;
        if (n >= N_NODES) break;
        float4 v = f[pass];
        int slot = gid[n] - g0;
        float m0 = (slot == 0) ? 1.f : 0.f;
        float m1 = (slot == 1) ? 1.f : 0.f;
        float m2 = (slot == 2) ? 1.f : 0.f;
        float m3 = (slot == 3) ? 1.f : 0.f;
        sa0.x += m0 * v.x; sa0.y += m0 * v.y; sa0.z += m0 * v.z; sa0.w += m0 * v.w;
        sa1.x += m1 * v.x; sa1.y += m1 * v.y; sa1.z += m1 * v.z; sa1.w += m1 * v.w;
        sa2.x += m2 * v.x; sa2.y += m2 * v.y; sa2.z += m2 * v.z; sa2.w += m2 * v.w;
        sa3.x += m3 * v.x; sa3.y += m3 * v.y; sa3.z += m3 * v.z; sa3.w += m3 * v.w;
        if (slot > 3) {                      // statistically never
            atomicAdd(&gsum[(g0 + slot) * 64 + lane * 4 + 0], v.x);
            atomicAdd(&gsum[(g0 + slot) * 64 + lane * 4 + 1], v.y);
            atomicAdd(&gsum[(g0 + slot) * 64 + lane * 4 + 2], v.z);
            atomicAdd(&gsum[(g0 + slot) * 64 + lane * 4 + 3], v.w);
        }
    }
    red4[(ng * 4 + 0) * 16 + lane] = sa0;
    red4[(ng * 4 + 1) * 16 + lane] = sa1;
    red4[(ng * 4 + 2) * 16 + lane] = sa2;
    red4[(ng * 4 + 3) * 16 + lane] = sa3;
    __syncthreads();
    const float* red = (const float*)red4;
    int slot = t >> 6, d = t & 63;
    float s = 0.f;
    for (int j = 0; j < 16; j++) s += red[(j * 4 + slot) * 64 + d];
    int g = g0 + slot;
    if (g < NUM_GRAPHS) atomicAdd(&gsum[g * 64 + d], s);
}

// ---------------- per-graph node counts ----------------
__global__ __launch_bounds__(256) void gcnt_k(const int* __restrict__ gid,
                                              float* __restrict__ gcnt) {
    __shared__ int h[NUM_GRAPHS];
    int b = blockIdx.x, t = threadIdx.x;
    if (t < NUM_GRAPHS) h[t] = 0;
    __syncthreads();
    int n = b * 256 + t;
    if (n < N_NODES) atomicAdd(&h[gid[n]], 1);
    __syncthreads();
    if (t < NUM_GRAPHS && h[t] > 0) atomicAdd(&gcnt[t], (float)h[t]);
}

__global__ __launch_bounds__(256) void final_k(const float* __restrict__ gsum,
                                               const float* __restrict__ gcnt,
                                               const float* __restrict__ b2,
                                               float* __restrict__ out) {
    int idx = blockIdx.x * 256 + threadIdx.x;
    if (idx >= NUM_GRAPHS * OUT_DIM) return;
    int d = idx & 63;
    float B2 = 0.f;
    for (int e = 0; e < N_ETYPES; e++) B2 += b2[e * OUT_DIM + d];
    float c = gcnt[idx >> 6];
    out[idx] = (gsum[idx] + c * B2) / fmaxf(c, 1.0f);
}

extern "C" void kernel_launch(void* const* d_in, const int* in_sizes, int n_in,
                              void* d_out, int out_size, void* d_ws, size_t ws_size,
                              hipStream_t stream) {
    const float* feat = (const float*)d_in[0];
    const int*   src  = (const int*)d_in[1];
    const int*   dst  = (const int*)d_in[2];
    const int*   gid  = (const int*)d_in[3];
    const float* W1   = (const float*)d_in[4];
    const float* b1   = (const float*)d_in[5];
    const float* W2   = (const float*)d_in[6];
    const float* b2   = (const float*)d_in[7];

    float* ws = (float*)d_ws;
    int*            HP   = (int*)ws;                         //   244,375 (pad 245,000)
    int*            OFFP = (int*)ws + 245000;                //   244,375 (pad 245,000)
    int*            BSUM = (int*)ws + 490000;                //   512
    float*          INV  = ws + 490512;                      //   500,000
    int*            NOFF = (int*)ws + 990512;                //   500,000
    int*            DEGN = (int*)ws + 1490512;               //   500,000
    unsigned short* FB32 = (unsigned short*)(ws + 1990512);  //   3.2M bf16 = 1,600,000 f
    float*          GSUM = ws + 3590512;                     //   4,096
    float*          GCNT = ws + 3594608;                     //   64
    unsigned*       EP   = (unsigned*)(ws + 3595000);        //   4,000,000
    unsigned short* AGG1B= (unsigned short*)(ws + 7595000);  //  16M bf16 = 8,000,000 f
                    // (written by agg1_k after sort_k; dead after gemm1_k)
    unsigned char*  T2F8 = (unsigned char*)(ws + 3595000);   //  32 MB fp8 = 8,000,000 f
                    // T2F8 aliases EP (dead after sort_k) + AGG1B[0:16MB] (dead after gemm1)
    unsigned short* H1B  = (unsigned short*)(ws + 15595000); //  12.8M bf16 = 6,400,000 f
    unsigned*       CSR  = (unsigned*)(ws + 21995000);       //   4,000,000
    unsigned short* W2TB = (unsigned short*)(ws + 25995000); //  40,960 bf16 = 20,480 f
    unsigned short* W1TB = (unsigned short*)(ws + 26015480); //  20,480 bf16 = 10,240 f
    float*          B1S  = ws + 26025720;                    //   128
    // total 26,025,848 floats = 104.1 MB

    hipMemsetAsync(GSUM, 0, (size_t)(4096 + 64) * sizeof(float), stream);

    cvt_feat_k<<<(N_NODES * FPAD + 255) / 256, 256, 0, stream>>>(feat, FB32);
    cvt_w2t_k<<<(N_ETYPES * OUT_DIM * HID_DIM + 255) / 256, 256, 0, stream>>>(W2, W2TB);
    cvt_w1t_k<<<(N_ETYPES * HID_DIM * 32 + 255) / 256, 256, 0, stream>>>(W1, W1TB);
    cvt_b1s_k<<<1, 128, 0, stream>>>(b1, B1S);
    part1_k<<<dim3(PBLK, N_ETYPES), 256, 0, stream>>>(dst, HP);
    scan1_k<<<SCAN_NBLK, 256, 0, stream>>>(HP, OFFP, BSUM);
    scan2_k<<<1, 256, 0, stream>>>(BSUM);
    scan3_k<<<(PN + 255) / 256, 256, 0, stream>>>(OFFP, BSUM);
    part2_k<<<dim3(PBLK, N_ETYPES), 256, 0, stream>>>(src, dst, OFFP, EP);
    sort_k<<<dim3(NBKT, N_ETYPES), 256, 0, stream>>>(OFFP, EP, CSR, NOFF, DEGN, INV);

    agg1_k<<<dim3(6250, N_ETYPES), 256, 0, stream>>>(NOFF, DEGN, CSR, FB32, INV, AGG1B);
    gemm1_k<<<(N_NODES + 63) / 64, 256, 0, stream>>>(AGG1B, W1TB, B1S, H1B);
    gemm2_k<<<(N_NODES + 63) / 64, 256, 0, stream>>>(H1B, W2TB, T2F8);
    gather2_k<<<dim3(NBKT, 8), 256, 0, stream>>>(NOFF, DEGN, INV, CSR, T2F8, gid, GSUM);

    gcnt_k<<<391, 256, 0, stream>>>(gid, GCNT);
    final_k<<<16, 256, 0, stream>>>(GSUM, GCNT, b2, (float*)d_out);
}

// Round 11
// 416.663 us; speedup vs baseline: 1.6176x; 1.0196x over previous
//
#include <hip/hip_runtime.h>

#define N_NODES   100000
#define N_EDGES   800000
#define N_ETYPES  5
#define IN_DIM    23
#define FPAD      32                    // feat dims padded to 32 (64 B bf16 rows = 1 line)
#define HID_DIM   128
#define OUT_DIM   64
#define NUM_GRAPHS 64
#define NBKT      391                   // ceil(100000/256) dst buckets of 256 nodes
#define PBLK      125                   // partition blocks per etype
#define CHUNK     6400                  // edges per partition block (125*6400 = 800000)
#define PN        (N_ETYPES*NBKT*PBLK)  // 244,375 histogram entries
#define SCAN_NBLK ((PN + 1023) / 1024)  // 239
#define TOT_EDGES (N_ETYPES*N_EDGES)    // 4,000,000
#define BKT_CAP   3072                  // max edges per (etype,bucket); mean 2048, sigma 45
#define ASTR      136                   // gemm2-phase LDS stride: conflict-free b128 frags
#define A1STR     40                    // gemm1-phase LDS stride: 2-way only (free)

// NOTE (measured r3): bulk LDS float atomics ~3.5 cyc/lane on gfx950 — pull-gather only.
// NOTE (measured r4/r5): L3 row-gather needs >=1500 blocks for occupancy/latency hiding.
// NOTE (measured r6): unpadded bf16 LDS tiles -> 16-way conflicts on MFMA ds_read_b128.
// NOTE (measured r7/r8): etype-outer + fp8 rows halved gather FETCH (470->251 MB); the
// remaining 251 MB is irreducible (per-XCD reuse ~1: 8x reuse split across 8 XCDs).
// NOTE (measured r9/r10): fp8 gather is miss-latency bound (41k lines/us vs ~51k
// achievable). This round: 8-lane uint2 rows -> 32 independent lines in flight/wave.

__device__ __forceinline__ unsigned short f2bf(float x) {
    unsigned u = __float_as_uint(x);
    unsigned r = (u + 0x7FFFu + ((u >> 16) & 1u)) >> 16;   // RNE
    return (unsigned short)r;
}
__device__ __forceinline__ float bf2f(unsigned short h) {
    return __uint_as_float(((unsigned)h) << 16);
}

typedef __attribute__((ext_vector_type(8))) short bf16x8;
typedef __attribute__((ext_vector_type(4))) float f32x4;
typedef __attribute__((ext_vector_type(2))) float f32x2;

// ---------------- feat -> bf16 table, padded to 32 dims (one line/row) ----------
__global__ __launch_bounds__(256) void cvt_feat_k(const float* __restrict__ feat,
                                                  unsigned short* __restrict__ fb32) {
    int i = blockIdx.x * 256 + threadIdx.x;
    if (i < N_NODES * FPAD) {
        int n = i >> 5, d = i & 31;
        fb32[i] = (d < IN_DIM) ? f2bf(feat[n * IN_DIM + d]) : (unsigned short)0;
    }
}

// ---------------- weight prep (merged): W2^T bf16, W1^T bf16 (k-pad 32), b1 sum ----
__global__ __launch_bounds__(256) void cvt_w_k(const float* __restrict__ W1,
                                               const float* __restrict__ b1,
                                               const float* __restrict__ W2,
                                               unsigned short* __restrict__ w1tb,
                                               unsigned short* __restrict__ w2tb,
                                               float* __restrict__ b1s) {
    int i = blockIdx.x * 256 + threadIdx.x;
    if (i < N_ETYPES * OUT_DIM * HID_DIM) {
        int e = i / (OUT_DIM * HID_DIM);
        int r = i - e * (OUT_DIM * HID_DIM);
        int n = r >> 7, k = r & 127;
        w2tb[i] = f2bf(W2[(e * HID_DIM + k) * OUT_DIM + n]);
    }
    if (i < N_ETYPES * HID_DIM * 32) {
        int e = i / (HID_DIM * 32);
        int r = i - e * (HID_DIM * 32);
        int n = r >> 5, k = r & 31;
        w1tb[i] = (k < IN_DIM) ? f2bf(W1[e * IN_DIM * HID_DIM + k * HID_DIM + n])
                               : (unsigned short)0;
    }
    if (i < HID_DIM) {
        float s = 0.f;
        for (int e = 0; e < N_ETYPES; e++) s += b1[e * HID_DIM + i];
        b1s[i] = s;
    }
}

// ---------------- partition pass 1: per-block bucket histogram ----------------
__global__ __launch_bounds__(256) void part1_k(const int* __restrict__ dst,
                                               int* __restrict__ hp) {
    __shared__ int hist[NBKT];
    int e = blockIdx.y, blk = blockIdx.x, t = threadIdx.x;
    for (int b = t; b < NBKT; b += 256) hist[b] = 0;
    __syncthreads();
    const int* dp = dst + e * N_EDGES + blk * CHUNK;
    for (int k = t; k < CHUNK; k += 256) atomicAdd(&hist[dp[k] >> 8], 1);
    __syncthreads();
    for (int b = t; b < NBKT; b += 256) hp[(e * NBKT + b) * PBLK + blk] = hist[b];
}

// ---------------- exclusive scan over 244,375 ----------------
__global__ __launch_bounds__(256) void scan1_k(const int* __restrict__ in,
                                               int* __restrict__ out,
                                               int* __restrict__ bsum) {
    __shared__ int ls[256];
    int t = threadIdx.x;
    int base = blockIdx.x * 1024 + t * 4;
    int v[4]; int s = 0;
    for (int j = 0; j < 4; j++) { int i = base + j; v[j] = (i < PN) ? in[i] : 0; s += v[j]; }
    ls[t] = s; __syncthreads();
    for (int o = 1; o < 256; o <<= 1) {
        int x = (t >= o) ? ls[t - o] : 0;
        __syncthreads();
        ls[t] += x;
        __syncthreads();
    }
    int run = (t > 0) ? ls[t - 1] : 0;
    if (t == 255) bsum[blockIdx.x] = ls[255];
    for (int j = 0; j < 4; j++) { int i = base + j; if (i < PN) out[i] = run; run += v[j]; }
}

__global__ __launch_bounds__(256) void scan2_k(int* __restrict__ bsum) {
    __shared__ int ls[256];
    int t = threadIdx.x;
    int v = (t < SCAN_NBLK) ? bsum[t] : 0;
    ls[t] = v; __syncthreads();
    for (int o = 1; o < 256; o <<= 1) {
        int x = (t >= o) ? ls[t - o] : 0;
        __syncthreads();
        ls[t] += x;
        __syncthreads();
    }
    if (t < SCAN_NBLK) bsum[t] = (t > 0) ? ls[t - 1] : 0;
}

__global__ __launch_bounds__(256) void scan3_k(int* __restrict__ off,
                                               const int* __restrict__ bsum) {
    int i = blockIdx.x * 256 + threadIdx.x;
    if (i < PN) off[i] += bsum[i >> 10];
}

// ---------------- partition pass 2: blocked contiguous scatter ----------------
__global__ __launch_bounds__(256) void part2_k(const int* __restrict__ src,
                                               const int* __restrict__ dst,
                                               const int* __restrict__ off,
                                               unsigned* __restrict__ ep) {
    __shared__ int cur[NBKT];
    int e = blockIdx.y, blk = blockIdx.x, t = threadIdx.x;
    for (int b = t; b < NBKT; b += 256) cur[b] = off[(e * NBKT + b) * PBLK + blk];
    __syncthreads();
    const int* dp = dst + e * N_EDGES + blk * CHUNK;
    const int* sp = src + e * N_EDGES + blk * CHUNK;
    for (int k = t; k < CHUNK; k += 256) {
        int d = dp[k], s = sp[k];
        int b = d >> 8;
        int pos = atomicAdd(&cur[b], 1);
        ep[pos] = (unsigned)s | ((unsigned)(d & 255) << 24);
    }
}

// ---------------- per-bucket counting sort -> node-sorted CSR + NOFF/DEG/INV ---
__global__ __launch_bounds__(256) void sort_k(const int* __restrict__ off,
                                              const unsigned* __restrict__ ep,
                                              unsigned* __restrict__ csr,
                                              int* __restrict__ noff,
                                              int* __restrict__ degn,
                                              float* __restrict__ inv) {
    __shared__ unsigned recs[BKT_CAP];
    __shared__ int hist[256];
    __shared__ int scn[256];
    __shared__ int curp[256];
    int b = blockIdx.x, e = blockIdx.y, t = threadIdx.x;
    int lin = (e * NBKT + b) * PBLK;
    int S = off[lin];
    int E = (lin == PN - PBLK) ? TOT_EDGES : off[lin + PBLK];
    int cnt = E - S;
    hist[t] = 0;
    __syncthreads();
    for (int i = t; i < cnt; i += 256) {
        unsigned r = ep[S + i];
        recs[i] = r;
        atomicAdd(&hist[r >> 24], 1);
    }
    __syncthreads();
    scn[t] = hist[t];
    __syncthreads();
    for (int o = 1; o < 256; o <<= 1) {
        int x = (t >= o) ? scn[t - o] : 0;
        __syncthreads();
        scn[t] += x;
        __syncthreads();
    }
    int excl = scn[t] - hist[t];
    curp[t] = excl;
    int n = b * 256 + t;
    if (n < N_NODES) {
        noff[e * N_NODES + n] = S + excl;
        degn[e * N_NODES + n] = hist[t];
        inv[e * N_NODES + n]  = 1.f / (float)(hist[t] + 1);
    }
    __syncthreads();
    for (int i = t; i < cnt; i += 256) {
        unsigned r = recs[i];
        int pos = atomicAdd(&curp[r >> 24], 1);
        csr[S + pos] = r & 0xFFFFFFu;
    }
}

// ---------------- layer1 pull-aggregate (self-term folded in, bf16 out) --------
__global__ __launch_bounds__(256) void agg1_k(const int* __restrict__ noff,
                                              const int* __restrict__ degn,
                                              const unsigned* __restrict__ csr,
                                              const unsigned short* __restrict__ fb32,
                                              const float* __restrict__ inv,
                                              unsigned short* __restrict__ agg1b) {
    int e = blockIdx.y;
    int t = threadIdx.x;
    int lane = t & 15;
    int n = blockIdx.x * 16 + (t >> 4);
    int idx = e * N_NODES + n;
    int st = noff[idx];
    int cnt = degn[idx];
    ushort2 sv = *(const ushort2*)&fb32[n * FPAD + lane * 2];   // self term
    float a0 = bf2f(sv.x), a1 = bf2f(sv.y);
    int k = 0;
    for (; k + 3 < cnt; k += 4) {
        int s0 = csr[st + k];
        int s1 = csr[st + k + 1];
        int s2 = csr[st + k + 2];
        int s3 = csr[st + k + 3];
        ushort2 v0 = *(const ushort2*)&fb32[s0 * FPAD + lane * 2];
        ushort2 v1 = *(const ushort2*)&fb32[s1 * FPAD + lane * 2];
        ushort2 v2 = *(const ushort2*)&fb32[s2 * FPAD + lane * 2];
        ushort2 v3 = *(const ushort2*)&fb32[s3 * FPAD + lane * 2];
        a0 += bf2f(v0.x) + bf2f(v1.x) + bf2f(v2.x) + bf2f(v3.x);
        a1 += bf2f(v0.y) + bf2f(v1.y) + bf2f(v2.y) + bf2f(v3.y);
    }
    for (; k < cnt; k++) {
        int s0 = csr[st + k];
        ushort2 v0 = *(const ushort2*)&fb32[s0 * FPAD + lane * 2];
        a0 += bf2f(v0.x);
        a1 += bf2f(v0.y);
    }
    float iv = inv[idx];
    ushort2 o; o.x = f2bf(a0 * iv); o.y = f2bf(a1 * iv);
    *(ushort2*)&agg1b[(size_t)idx * 32 + lane * 2] = o;
}

// ---------------- fused MLP (MFMA bf16): H1 = relu(sum_e AGG1B_e@W1_e + B1) kept in
// LDS, then t2f8_e = fp8(H1 @ W2_e) — no H1 global round-trip. Block = 64 nodes.
// Phase-1 tiles (As1/Wt1, A1STR pad) alias phase-2 Wt2 storage; H1s uses ASTR pad.
__global__ __launch_bounds__(256) void gemm12_k(const unsigned short* __restrict__ agg1b,
                                                const unsigned short* __restrict__ w1tb,
                                                const float* __restrict__ b1s,
                                                const unsigned short* __restrict__ w2tb,
                                                unsigned char* __restrict__ t2f8) {
    __shared__ unsigned short H1s[64 * ASTR];   // 17.4 KB [node][k]
    __shared__ unsigned short Wt2[64 * ASTR];   // 17.4 KB; phase1 aliases:
    unsigned short* As1 = Wt2;                  //   [64*A1STR]  = 2560 ushorts
    unsigned short* Wt1 = Wt2 + 64 * A1STR;     //   [128*A1STR] = 5120 (7680 <= 8704 ok)
    int t = threadIdx.x;
    int node0 = blockIdx.x * 64;
    int w = t >> 6, lane = t & 63;
    int m = lane & 15, quad = lane >> 4;

    // ---- phase 1: H1 = relu(sum_e A_e @ W1_e + b1s)
    f32x4 acc[8];
    for (int nt = 0; nt < 8; nt++) {
        float bb = b1s[nt * 16 + m];
        f32x4 c = {bb, bb, bb, bb};
        acc[nt] = c;
    }
    for (int e = 0; e < N_ETYPES; e++) {
        __syncthreads();
        for (int j = t; j < 64 * 8; j += 256) {
            int n = j >> 3, c4 = (j & 7) * 4;
            int gn = node0 + n;
            int cn = gn < N_NODES ? gn : N_NODES - 1;
            *(ushort4*)&As1[n * A1STR + c4] =
                *(const ushort4*)&agg1b[(size_t)(e * N_NODES + cn) * 32 + c4];
        }
        for (int j = t; j < 128 * 8; j += 256) {
            int n = j >> 3, c4 = (j & 7) * 4;
            *(ushort4*)&Wt1[n * A1STR + c4] =
                *(const ushort4*)&w1tb[(size_t)(e * HID_DIM + n) * 32 + c4];
        }
        __syncthreads();
        bf16x8 a = *(const bf16x8*)&As1[(w * 16 + m) * A1STR + quad * 8];
        for (int nt = 0; nt < 8; nt++) {
            bf16x8 b = *(const bf16x8*)&Wt1[(nt * 16 + m) * A1STR + quad * 8];
            acc[nt] = __builtin_amdgcn_mfma_f32_16x16x32_bf16(a, b, acc[nt], 0, 0, 0);
        }
    }
    __syncthreads();                           // done reading As1/Wt1 (aliases Wt2)
    for (int nt = 0; nt < 8; nt++)
        for (int r = 0; r < 4; r++)
            H1s[(w * 16 + quad * 4 + r) * ASTR + nt * 16 + m] =
                f2bf(fmaxf(acc[nt][r], 0.f));
    __syncthreads();

    // ---- phase 2: t2_e = fp8(H1 @ W2_e)
    bf16x8 a2[4];
    for (int ks = 0; ks < 4; ks++)
        a2[ks] = *(const bf16x8*)&H1s[(w * 16 + m) * ASTR + ks * 32 + quad * 8];
    for (int e = 0; e < N_ETYPES; e++) {
        __syncthreads();                       // protect Wt2 from prev readers
        for (int j = t; j < 64 * 32; j += 256) {
            int n = j >> 5, c4 = (j & 31) * 4;
            *(ushort4*)&Wt2[n * ASTR + c4] =
                *(const ushort4*)&w2tb[(e * OUT_DIM + n) * HID_DIM + c4];
        }
        __syncthreads();
        unsigned char* out = t2f8 + (size_t)e * N_NODES * OUT_DIM;
        for (int nt = 0; nt < 4; nt++) {
            f32x4 c = {0.f, 0.f, 0.f, 0.f};
            for (int ks = 0; ks < 4; ks++) {
                bf16x8 b = *(const bf16x8*)&Wt2[(nt * 16 + m) * ASTR + ks * 32 + quad * 8];
                c = __builtin_amdgcn_mfma_f32_16x16x32_bf16(a2[ks], b, c, 0, 0, 0);
            }
            for (int r = 0; r < 4; r++) {
                int gn = node0 + w * 16 + quad * 4 + r;
                if (gn < N_NODES) {
                    int p = __builtin_amdgcn_cvt_pk_fp8_f32(c[r], c[r], 0, false);
                    out[(size_t)gn * OUT_DIM + nt * 16 + m] = (unsigned char)(p & 0xFF);
                }
            }
        }
    }
}

// ---------------- layer2 pull + per-graph pool; 8 lanes x uint2 per fp8 row ------
// grid (NBKT, 8): block = 32 nodes, one node per 8-lane group (no pass loop).
// 32 independent lines in flight per wave (8 rows x unroll 4).
__global__ __launch_bounds__(256) void gather2_k(const int* __restrict__ noff,
                                                 const int* __restrict__ degn,
                                                 const float* __restrict__ inv,
                                                 const unsigned* __restrict__ csr,
                                                 const unsigned char* __restrict__ t2f8,
                                                 const int* __restrict__ gid,
                                                 float* __restrict__ gsum) {
    __shared__ float red[32 * 64];          // 8 KB [node][dim]
    __shared__ int slotl[32];
    int b = blockIdx.x, qb = blockIdx.y, t = threadIdx.x;
    int lane = t & 7, ng = t >> 3;
    int nbase = b * 256 + qb * 32;
    int gbase = nbase < N_NODES ? nbase : N_NODES - 1;
    int g0 = gid[gbase];
    if (t < 32) {
        int nn = nbase + t;
        slotl[t] = (nn < N_NODES) ? gid[nn] - g0 : -1;
    }
    __syncthreads();
    int n = nbase + ng;
    float f0=0,f1=0,f2=0,f3=0,f4=0,f5=0,f6=0,f7=0;
    if (n < N_NODES) {
        for (int e = 0; e < N_ETYPES; e++) {
            const unsigned char* base = t2f8 + (size_t)e * N_NODES * OUT_DIM;
            int idx = e * N_NODES + n;
            int st = noff[idx];
            int cnt = degn[idx];
            float iv = inv[idx];
            uint2 rv = *(const uint2*)&base[(size_t)n * OUT_DIM + lane * 8];
            f32x2 l0 = __builtin_amdgcn_cvt_pk_f32_fp8((int)rv.x, false);
            f32x2 h0 = __builtin_amdgcn_cvt_pk_f32_fp8((int)rv.x, true);
            f32x2 l1 = __builtin_amdgcn_cvt_pk_f32_fp8((int)rv.y, false);
            f32x2 h1 = __builtin_amdgcn_cvt_pk_f32_fp8((int)rv.y, true);
            float a0=l0.x,a1=l0.y,a2=h0.x,a3=h0.y,a4=l1.x,a5=l1.y,a6=h1.x,a7=h1.y;
            int k = 0;
            for (; k + 3 < cnt; k += 4) {
                int sA = csr[st + k];
                int sB = csr[st + k + 1];
                int sC = csr[st + k + 2];
                int sD = csr[st + k + 3];
                uint2 rA = *(const uint2*)&base[(size_t)sA * OUT_DIM + lane * 8];
                uint2 rB = *(const uint2*)&base[(size_t)sB * OUT_DIM + lane * 8];
                uint2 rC = *(const uint2*)&base[(size_t)sC * OUT_DIM + lane * 8];
                uint2 rD = *(const uint2*)&base[(size_t)sD * OUT_DIM + lane * 8];
                f32x2 v;
                v = __builtin_amdgcn_cvt_pk_f32_fp8((int)rA.x, false); a0+=v.x; a1+=v.y;
                v = __builtin_amdgcn_cvt_pk_f32_fp8((int)rA.x, true);  a2+=v.x; a3+=v.y;
                v = __builtin_amdgcn_cvt_pk_f32_fp8((int)rA.y, false); a4+=v.x; a5+=v.y;
                v = __builtin_amdgcn_cvt_pk_f32_fp8((int)rA.y, true);  a6+=v.x; a7+=v.y;
                v = __builtin_amdgcn_cvt_pk_f32_fp8((int)rB.x, false); a0+=v.x; a1+=v.y;
                v = __builtin_amdgcn_cvt_pk_f32_fp8((int)rB.x, true);  a2+=v.x; a3+=v.y;
                v = __builtin_amdgcn_cvt_pk_f32_fp8((int)rB.y, false); a4+=v.x; a5+=v.y;
                v = __builtin_amdgcn_cvt_pk_f32_fp8((int)rB.y, true);  a6+=v.x; a7+=v.y;
                v = __builtin_amdgcn_cvt_pk_f32_fp8((int)rC.x, false); a0+=v.x; a1+=v.y;
                v = __builtin_amdgcn_cvt_pk_f32_fp8((int)rC.x, true);  a2+=v.x; a3+=v.y;
                v = __builtin_amdgcn_cvt_pk_f32_fp8((int)rC.y, false); a4+=v.x; a5+=v.y;
                v = __builtin_amdgcn_cvt_pk_f32_fp8((int)rC.y, true);  a6+=v.x; a7+=v.y;
                v = __builtin_amdgcn_cvt_pk_f32_fp8((int)rD.x, false); a0+=v.x; a1+=v.y;
                v = __builtin_amdgcn_cvt_pk_f32_fp8((int)rD.x, true);  a2+=v.x; a3+=v.y;
                v = __builtin_amdgcn_cvt_pk_f32_fp8((int)rD.y, false); a4+=v.x; a5+=v.y;
                v = __builtin_amdgcn_cvt_pk_f32_fp8((int)rD.y, true);  a6+=v.x; a7+=v.y;
            }
            for (; k < cnt; k++) {
                int sA = csr[st + k];
                uint2 rA = *(const uint2*)&base[(size_t)sA * OUT_DIM + lane * 8];
                f32x2 v;
                v = __builtin_amdgcn_cvt_pk_f32_fp8((int)rA.x, false); a0+=v.x; a1+=v.y;
                v = __builtin_amdgcn_cvt_pk_f32_fp8((int)rA.x, true);  a2+=v.x; a3+=v.y;
                v = __builtin_amdgcn_cvt_pk_f32_fp8((int)rA.y, false); a4+=v.x; a5+=v.y;
                v = __builtin_amdgcn_cvt_pk_f32_fp8((int)rA.y, true);  a6+=v.x; a7+=v.y;
            }
            f0+=iv*a0; f1+=iv*a1; f2+=iv*a2; f3+=iv*a3;
            f4+=iv*a4; f5+=iv*a5; f6+=iv*a6; f7+=iv*a7;
        }
    }
    int slot = slotl[ng];
    if (slot > 3 && n < N_NODES) {          // statistically never (graphs ~1563 nodes)
        int gbase8 = (g0 + slot) * 64 + lane * 8;
        atomicAdd(&gsum[gbase8 + 0], f0); atomicAdd(&gsum[gbase8 + 1], f1);
        atomicAdd(&gsum[gbase8 + 2], f2); atomicAdd(&gsum[gbase8 + 3], f3);
        atomicAdd(&gsum[gbase8 + 4], f4); atomicAdd(&gsum[gbase8 + 5], f5);
        atomicAdd(&gsum[gbase8 + 6], f6); atomicAdd(&gsum[gbase8 + 7], f7);
        f0=f1=f2=f3=f4=f5=f6=f7=0.f;
    }
    *(float4*)&red[ng * 64 + lane * 8]     = make_float4(f0, f1, f2, f3);
    *(float4*)&red[ng * 64 + lane * 8 + 4] = make_float4(f4, f5, f6, f7);
    __syncthreads();
    int slot2 = t >> 6, d = t & 63;
    float s = 0.f;
    for (int j = 0; j < 32; j++)
        s += (slotl[j] == slot2) ? red[j * 64 + d] : 0.f;
    int g = g0 + slot2;
    if (g < NUM_GRAPHS) atomicAdd(&gsum[g * 64 + d], s);
}

// ---------------- per-graph node counts ----------------
__global__ __launch_bounds__(256) void gcnt_k(const int* __restrict__ gid,
                                              float* __restrict__ gcnt) {
    __shared__ int h[NUM_GRAPHS];
    int b = blockIdx.x, t = threadIdx.x;
    if (t < NUM_GRAPHS) h[t] = 0;
    __syncthreads();
    int n = b * 256 + t;
    if (n < N_NODES) atomicAdd(&h[gid[n]], 1);
    __syncthreads();
    if (t < NUM_GRAPHS && h[t] > 0) atomicAdd(&gcnt[t], (float)h[t]);
}

__global__ __launch_bounds__(256) void final_k(const float* __restrict__ gsum,
                                               const float* __restrict__ gcnt,
                                               const float* __restrict__ b2,
                                               float* __restrict__ out) {
    int idx = blockIdx.x * 256 + threadIdx.x;
    if (idx >= NUM_GRAPHS * OUT_DIM) return;
    int d = idx & 63;
    float B2 = 0.f;
    for (int e = 0; e < N_ETYPES; e++) B2 += b2[e * OUT_DIM + d];
    float c = gcnt[idx >> 6];
    out[idx] = (gsum[idx] + c * B2) / fmaxf(c, 1.0f);
}

extern "C" void kernel_launch(void* const* d_in, const int* in_sizes, int n_in,
                              void* d_out, int out_size, void* d_ws, size_t ws_size,
                              hipStream_t stream) {
    const float* feat = (const float*)d_in[0];
    const int*   src  = (const int*)d_in[1];
    const int*   dst  = (const int*)d_in[2];
    const int*   gid  = (const int*)d_in[3];
    const float* W1   = (const float*)d_in[4];
    const float* b1   = (const float*)d_in[5];
    const float* W2   = (const float*)d_in[6];
    const float* b2   = (const float*)d_in[7];

    float* ws = (float*)d_ws;
    int*            HP   = (int*)ws;                         //   244,375 (pad 245,000)
    int*            OFFP = (int*)ws + 245000;                //   244,375 (pad 245,000)
    int*            BSUM = (int*)ws + 490000;                //   512
    float*          INV  = ws + 490512;                      //   500,000
    int*            NOFF = (int*)ws + 990512;                //   500,000
    int*            DEGN = (int*)ws + 1490512;               //   500,000
    unsigned short* FB32 = (unsigned short*)(ws + 1990512);  //   3.2M bf16 = 1,600,000 f
    float*          GSUM = ws + 3590512;                     //   4,096
    float*          GCNT = ws + 3594608;                     //   64
    unsigned*       EP   = (unsigned*)(ws + 3595000);        //   4,000,000
    unsigned short* AGG1B= (unsigned short*)(ws + 7595000);  //  16M bf16 = 8,000,000 f
                    // (written by agg1_k after sort_k; dead after gemm12_k phase 1)
    unsigned char*  T2F8 = (unsigned char*)(ws + 3595000);   //  32 MB fp8 = 8,000,000 f
                    // T2F8 aliases EP (dead after sort_k) + AGG1B[0:16MB]... NOTE:
                    // gemm12 reads AGG1B (phase1) while writing T2F8 — they must NOT
                    // overlap. T2F8 [3595000,11595000) vs AGG1B [7595000,15595000):
                    // OVERLAP [7595000,11595000) — move T2F8 after AGG1B instead:
    T2F8 = (unsigned char*)(ws + 15595000);                  //  32 MB = 8,000,000 f
    unsigned*       CSR  = (unsigned*)(ws + 23595000);       //   4,000,000
    unsigned short* W2TB = (unsigned short*)(ws + 27595000); //  40,960 bf16 = 20,480 f
    unsigned short* W1TB = (unsigned short*)(ws + 27615480); //  20,480 bf16 = 10,240 f
    float*          B1S  = ws + 27625720;                    //   128
    // total 27,625,848 floats = 110.5 MB

    hipMemsetAsync(GSUM, 0, (size_t)(4096 + 64) * sizeof(float), stream);

    cvt_feat_k<<<(N_NODES * FPAD + 255) / 256, 256, 0, stream>>>(feat, FB32);
    cvt_w_k<<<(N_ETYPES * OUT_DIM * HID_DIM + 255) / 256, 256, 0, stream>>>(
        W1, b1, W2, W1TB, W2TB, B1S);
    part1_k<<<dim3(PBLK, N_ETYPES), 256, 0, stream>>>(dst, HP);
    scan1_k<<<SCAN_NBLK, 256, 0, stream>>>(HP, OFFP, BSUM);
    scan2_k<<<1, 256, 0, stream>>>(BSUM);
    scan3_k<<<(PN + 255) / 256, 256, 0, stream>>>(OFFP, BSUM);
    part2_k<<<dim3(PBLK, N_ETYPES), 256, 0, stream>>>(src, dst, OFFP, EP);
    sort_k<<<dim3(NBKT, N_ETYPES), 256, 0, stream>>>(OFFP, EP, CSR, NOFF, DEGN, INV);

    agg1_k<<<dim3(6250, N_ETYPES), 256, 0, stream>>>(NOFF, DEGN, CSR, FB32, INV, AGG1B);
    gemm12_k<<<(N_NODES + 63) / 64, 256, 0, stream>>>(AGG1B, W1TB, B1S, W2TB, T2F8);
    gather2_k<<<dim3(NBKT, 8), 256, 0, stream>>>(NOFF, DEGN, INV, CSR, T2F8, gid, GSUM);

    gcnt_k<<<391, 256, 0, stream>>>(gid, GCNT);
    final_k<<<16, 256, 0, stream>>>(GSUM, GCNT, b2, (float*)d_out);
}